// Round 2
// baseline (1064.452 us; speedup 1.0000x reference)
//
#include <hip/hip_runtime.h>
#include <stdint.h>

typedef __bf16 bf16;
typedef __bf16 bf16x8 __attribute__((ext_vector_type(8)));
typedef __bf16 bf16x4 __attribute__((ext_vector_type(4)));
typedef float f32x4 __attribute__((ext_vector_type(4)));

#define MFMA16(a, b, c) __builtin_amdgcn_mfma_f32_16x16x32_bf16(a, b, c, 0, 0, 0)

// ---------------------------------------------------------------------------
// Weight transpose + fp32->bf16 convert:  out[n][k] = (bf16) in[k][n]
// ---------------------------------------------------------------------------
__global__ __launch_bounds__(256) void transpose_w(const float* __restrict__ in,
                                                   bf16* __restrict__ out, int N) {
  __shared__ float tile[32][33];
  const int n0 = blockIdx.x * 32, k0 = blockIdx.y * 32;
  const int tx = threadIdx.x, ty = threadIdx.y;
#pragma unroll
  for (int i = 0; i < 4; ++i)
    tile[ty * 4 + i][tx] = in[(size_t)(k0 + ty * 4 + i) * N + n0 + tx];
  __syncthreads();
#pragma unroll
  for (int i = 0; i < 4; ++i)
    out[(size_t)(n0 + ty * 4 + i) * 512 + k0 + tx] = (bf16)tile[tx][ty * 4 + i];
}

// ---------------------------------------------------------------------------
// LayerNorm: x (57344 x 512) fp32 -> h bf16, scale-contiguous row blocks
// ---------------------------------------------------------------------------
__global__ __launch_bounds__(256) void ln_kernel(const float* __restrict__ x,
                                                 const float* __restrict__ gamma,
                                                 const float* __restrict__ beta,
                                                 bf16* __restrict__ h) {
  const int t = threadIdx.x, lane = t & 63, w = t >> 6;
  const int row = blockIdx.x * 4 + w;
  const float* xr = x + (size_t)row * 512 + lane * 8;
  float4 v0 = *(const float4*)xr;
  float4 v1 = *(const float4*)(xr + 4);
  float s = v0.x + v0.y + v0.z + v0.w + v1.x + v1.y + v1.z + v1.w;
  float q = v0.x * v0.x + v0.y * v0.y + v0.z * v0.z + v0.w * v0.w +
            v1.x * v1.x + v1.y * v1.y + v1.z * v1.z + v1.w * v1.w;
#pragma unroll
  for (int off = 1; off < 64; off <<= 1) {
    s += __shfl_xor(s, off);
    q += __shfl_xor(q, off);
  }
  const float mean = s * (1.0f / 512.0f);
  const float var = q * (1.0f / 512.0f) - mean * mean;
  const float rs = rsqrtf(var + 1e-5f);
  float4 g0 = *(const float4*)(gamma + lane * 8);
  float4 g1 = *(const float4*)(gamma + lane * 8 + 4);
  float4 b0 = *(const float4*)(beta + lane * 8);
  float4 b1 = *(const float4*)(beta + lane * 8 + 4);
  const int bb = row / 3584;
  const int sp = row - bb * 3584;
  size_t drow;
  if (sp < 512)
    drow = (size_t)bb * 512 + sp;
  else if (sp < 1536)
    drow = 8192 + (size_t)bb * 1024 + (sp - 512);
  else
    drow = 24576 + (size_t)bb * 2048 + (sp - 1536);
  bf16x8 ov = {(bf16)((v0.x - mean) * rs * g0.x + b0.x),
               (bf16)((v0.y - mean) * rs * g0.y + b0.y),
               (bf16)((v0.z - mean) * rs * g0.z + b0.z),
               (bf16)((v0.w - mean) * rs * g0.w + b0.w),
               (bf16)((v1.x - mean) * rs * g1.x + b1.x),
               (bf16)((v1.y - mean) * rs * g1.y + b1.y),
               (bf16)((v1.z - mean) * rs * g1.z + b1.z),
               (bf16)((v1.w - mean) * rs * g1.w + b1.w)};
  *(bf16x8*)(h + drow * 512 + lane * 8) = ov;
}

// ---------------------------------------------------------------------------
// QKV GEMM (unchanged this round)
// ---------------------------------------------------------------------------
__global__ __launch_bounds__(256) void qkv_gemm(const bf16* __restrict__ A,
                                                const bf16* __restrict__ Bt,
                                                const float* __restrict__ bias,
                                                bf16* __restrict__ qk,
                                                bf16* __restrict__ vt, int l2L) {
  __shared__ bf16 As[128 * 64];
  __shared__ bf16 Bs[128 * 64];
  const int t = threadIdx.x, lane = t & 63, w = t >> 6;
  const int wm = w >> 1, wn = w & 1;
  const int m0 = blockIdx.x * 128, n0 = blockIdx.y * 128;
  const int L = 1 << l2L;

  f32x4 acc[4][4];
#pragma unroll
  for (int i = 0; i < 4; ++i)
#pragma unroll
    for (int j = 0; j < 4; ++j) acc[i][j] = (f32x4)0.0f;

  const int srow = t >> 3;
  const int sc = t & 7;

  for (int kt = 0; kt < 8; ++kt) {
    const int k0 = kt * 64;
#pragma unroll
    for (int i = 0; i < 4; ++i) {
      const int row = i * 32 + srow;
      uint4 va = *(const uint4*)(A + (size_t)(m0 + row) * 512 + k0 + sc * 8);
      uint4 vb = *(const uint4*)(Bt + (size_t)(n0 + row) * 512 + k0 + sc * 8);
      *(uint4*)((char*)As + row * 128 + ((sc ^ (row & 7)) << 4)) = va;
      *(uint4*)((char*)Bs + row * 128 + ((sc ^ (row & 7)) << 4)) = vb;
    }
    __syncthreads();
#pragma unroll
    for (int kk = 0; kk < 2; ++kk) {
      bf16x8 af[4], bfr[4];
#pragma unroll
      for (int mi = 0; mi < 4; ++mi) {
        const int r = wm * 64 + mi * 16 + (lane & 15);
        const int ch = kk * 4 + (lane >> 4);
        af[mi] = *(const bf16x8*)((const char*)As + r * 128 + ((ch ^ (r & 7)) << 4));
      }
#pragma unroll
      for (int ni = 0; ni < 4; ++ni) {
        const int r = wn * 64 + ni * 16 + (lane & 15);
        const int ch = kk * 4 + (lane >> 4);
        bfr[ni] = *(const bf16x8*)((const char*)Bs + r * 128 + ((ch ^ (r & 7)) << 4));
      }
#pragma unroll
      for (int mi = 0; mi < 4; ++mi)
#pragma unroll
        for (int ni = 0; ni < 4; ++ni)
          acc[mi][ni] = MFMA16(af[mi], bfr[ni], acc[mi][ni]);
    }
    __syncthreads();
  }

  const bool isV = (n0 >= 1024);
#pragma unroll
  for (int ni = 0; ni < 4; ++ni) {
    const int col = n0 + wn * 64 + ni * 16 + (lane & 15);
    const float bv = bias[col];
#pragma unroll
    for (int mi = 0; mi < 4; ++mi) {
      const int rb = m0 + wm * 64 + mi * 16 + ((lane >> 4) << 2);
      if (!isV) {
#pragma unroll
        for (int r = 0; r < 4; ++r)
          qk[(size_t)(rb + r) * 1024 + col] = (bf16)(acc[mi][ni][r] + bv);
      } else {
        const int d = col - 1024;
        const int bi = rb >> l2L;
        const int kv = rb & (L - 1);
        bf16x4 pk = {(bf16)(acc[mi][ni][0] + bv), (bf16)(acc[mi][ni][1] + bv),
                     (bf16)(acc[mi][ni][2] + bv), (bf16)(acc[mi][ni][3] + bv)};
        *(bf16x4*)(vt + ((size_t)bi * 512 + d) * L + kv) = pk;
      }
    }
  }
}

// ---------------------------------------------------------------------------
// Flash attention, one scale. grid = 16 * (L/32), block = 512 (8 waves).
// Q tile 32 rows LDS-resident. LDS ~52KB -> 2 blocks/CU (was 1).
// XCD chunk-swizzle: each XCD handles 2 batches -> K/V L2 locality.
// S^T = K*Q^T (K direct from L2), in-reg online softmax w/ cross-wave LDS
// exchange, O^T = V^T * P^T (V^T direct from L2, P via LDS).
// ---------------------------------------------------------------------------
__global__ __launch_bounds__(512, 4) void attn(const bf16* __restrict__ qkbuf,
                                               const bf16* __restrict__ vt,
                                               bf16* __restrict__ o, int l2L,
                                               float scale, int nwg) {
  __shared__ bf16 Qs[32 * 512];   // 32KB, swizzled
  __shared__ bf16 Ps[32 * 264];   // 16.9KB, padded stride
  __shared__ float cmax[8][32];
  __shared__ float csum[8][32];
  __shared__ float mrow[32];
  __shared__ float lrow[32];
  __shared__ float frow[32];

  const int t = threadIdx.x, lane = t & 63, w = t >> 6;
  const int L = 1 << l2L;
  // bijective XCD chunk swizzle (nwg % 8 == 0): XCD x gets logical chunk x
  const int lg = ((blockIdx.x & 7) * (nwg >> 3)) + (blockIdx.x >> 3);
  const int qtpb = l2L - 5;              // log2(q-tiles per batch)
  const int b = lg >> qtpb;
  const int qt = lg & ((1 << qtpb) - 1);

  const bf16* qbase = qkbuf + ((size_t)b * L + qt * 32) * 1024;
  const bf16* kbase = qkbuf + (size_t)b * L * 1024 + 512;
  const bf16* vbase = vt + (size_t)b * 512 * L;

  // stage Q (swizzled): 32 rows, 4 per wave
#pragma unroll
  for (int i = 0; i < 4; ++i) {
    const int row = i * 8 + w;
    uint4 v = *(const uint4*)(qbase + (size_t)row * 1024 + lane * 8);
    *(uint4*)((char*)Qs + row * 1024 + ((lane ^ (row & 7)) << 4)) = v;
  }
  if (t < 32) {
    mrow[t] = -INFINITY;
    lrow[t] = 0.0f;
  }
  __syncthreads();

  f32x4 oacc[4][2];  // [dt][qg]: d = w*64+dt*16+(l>>4)*4+r, q = qg*16+(l&15)
#pragma unroll
  for (int i = 0; i < 4; ++i)
#pragma unroll
    for (int j = 0; j < 2; ++j) oacc[i][j] = (f32x4)0.0f;

  const float L2E = 1.44269504088896f;
  const int nmega = L >> 8;
  for (int mg = 0; mg < nmega; ++mg) {
    const int kvw = mg * 256 + w * 32;  // this wave's kv slice
    f32x4 st[2][2];
#pragma unroll
    for (int i = 0; i < 2; ++i)
#pragma unroll
      for (int j = 0; j < 2; ++j) st[i][j] = (f32x4)0.0f;

    const bf16* kr = kbase + (size_t)kvw * 1024;
    for (int ks = 0; ks < 16; ++ks) {
      bf16x8 af[2], bq[2];
#pragma unroll
      for (int kt = 0; kt < 2; ++kt)
        af[kt] = *(const bf16x8*)(kr + (size_t)(kt * 16 + (lane & 15)) * 1024 +
                                  ks * 32 + ((lane >> 4) << 3));
#pragma unroll
      for (int qg = 0; qg < 2; ++qg) {
        const int qr = qg * 16 + (lane & 15);
        const int ch = ks * 4 + (lane >> 4);
        bq[qg] = *(const bf16x8*)((const char*)Qs + qr * 1024 +
                                  ((ch ^ (qr & 7)) << 4));
      }
#pragma unroll
      for (int kt = 0; kt < 2; ++kt)
#pragma unroll
        for (int qg = 0; qg < 2; ++qg)
          st[kt][qg] = MFMA16(af[kt], bq[qg], st[kt][qg]);
    }
#pragma unroll
    for (int kt = 0; kt < 2; ++kt)
#pragma unroll
      for (int qg = 0; qg < 2; ++qg) st[kt][qg] *= scale;

    // per-q (column) max of this wave's kv slice
#pragma unroll
    for (int qg = 0; qg < 2; ++qg) {
      float vm = -INFINITY;
#pragma unroll
      for (int kt = 0; kt < 2; ++kt)
#pragma unroll
        for (int r = 0; r < 4; ++r) vm = fmaxf(vm, st[kt][qg][r]);
      vm = fmaxf(vm, __shfl_xor(vm, 16));
      vm = fmaxf(vm, __shfl_xor(vm, 32));
      if (lane < 16) cmax[w][qg * 16 + lane] = vm;
    }
    __syncthreads();  // B1
    if (t < 32) {
      const float mo = mrow[t];
      float mn = mo;
#pragma unroll
      for (int j = 0; j < 8; ++j) mn = fmaxf(mn, cmax[j][t]);
      frow[t] = exp2f((mo - mn) * L2E);
      mrow[t] = mn;
    }
    __syncthreads();  // B2
#pragma unroll
    for (int qg = 0; qg < 2; ++qg) {
      const float mq = mrow[qg * 16 + (lane & 15)] * L2E;
      const float fq = frow[qg * 16 + (lane & 15)];
      float ssum = 0.0f;
#pragma unroll
      for (int kt = 0; kt < 2; ++kt) {
        const float p0 = exp2f(st[kt][qg][0] * L2E - mq);
        const float p1 = exp2f(st[kt][qg][1] * L2E - mq);
        const float p2 = exp2f(st[kt][qg][2] * L2E - mq);
        const float p3 = exp2f(st[kt][qg][3] * L2E - mq);
        ssum += p0 + p1 + p2 + p3;
        bf16x4 pk = {(bf16)p0, (bf16)p1, (bf16)p2, (bf16)p3};
        const int q = qg * 16 + (lane & 15);
        const int kvl = w * 32 + kt * 16 + ((lane >> 4) << 2);
        *(bf16x4*)(Ps + (size_t)q * 264 + kvl) = pk;
      }
      ssum += __shfl_xor(ssum, 16);
      ssum += __shfl_xor(ssum, 32);
      if (lane < 16) csum[w][qg * 16 + lane] = ssum;
#pragma unroll
      for (int dt = 0; dt < 4; ++dt) oacc[dt][qg] *= fq;
    }
    __syncthreads();  // B3
    if (t < 32) {
      float l = lrow[t] * frow[t];
#pragma unroll
      for (int j = 0; j < 8; ++j) l += csum[j][t];
      lrow[t] = l;
    }
    // PV: O^T += V^T * P^T over this mega-span (256 kv)
#pragma unroll
    for (int ks = 0; ks < 8; ++ks) {
      bf16x8 av[4], bp[2];
#pragma unroll
      for (int dt = 0; dt < 4; ++dt)
        av[dt] = *(const bf16x8*)(vbase +
                                  (size_t)(w * 64 + dt * 16 + (lane & 15)) * L +
                                  mg * 256 + ks * 32 + ((lane >> 4) << 3));
#pragma unroll
      for (int qg = 0; qg < 2; ++qg)
        bp[qg] = *(const bf16x8*)(Ps + (size_t)(qg * 16 + (lane & 15)) * 264 +
                                  ks * 32 + ((lane >> 4) << 3));
#pragma unroll
      for (int dt = 0; dt < 4; ++dt)
#pragma unroll
        for (int qg = 0; qg < 2; ++qg)
          oacc[dt][qg] = MFMA16(av[dt], bp[qg], oacc[dt][qg]);
    }
    // next iter's first LDS writes (cmax) are gated by B1; Ps writes by B2.
  }

  __syncthreads();
  if (t < 32) frow[t] = 1.0f / lrow[t];
  __syncthreads();
#pragma unroll
  for (int qg = 0; qg < 2; ++qg) {
    const float inv = frow[qg * 16 + (lane & 15)];
    const size_t orow = (size_t)b * L + qt * 32 + qg * 16 + (lane & 15);
#pragma unroll
    for (int dt = 0; dt < 4; ++dt) {
      bf16x4 pk = {(bf16)(oacc[dt][qg][0] * inv), (bf16)(oacc[dt][qg][1] * inv),
                   (bf16)(oacc[dt][qg][2] * inv), (bf16)(oacc[dt][qg][3] * inv)};
      *(bf16x4*)(o + orow * 512 + w * 64 + dt * 16 + ((lane >> 4) << 2)) = pk;
    }
  }
}

// ---------------------------------------------------------------------------
// Out projection (unchanged this round)
// ---------------------------------------------------------------------------
__device__ __forceinline__ int row2g(int row) {
  if (row < 8192) return ((row >> 9) * 3584) + (row & 511);
  if (row < 24576) {
    const int r = row - 8192;
    return ((r >> 10) * 3584) + 512 + (r & 1023);
  }
  const int r = row - 24576;
  return ((r >> 11) * 3584) + 1536 + (r & 2047);
}

__global__ __launch_bounds__(256) void out_gemm(const bf16* __restrict__ A,
                                                const bf16* __restrict__ Bt,
                                                const float* __restrict__ bias,
                                                const float* __restrict__ x,
                                                float* __restrict__ out) {
  __shared__ bf16 As[128 * 64];
  __shared__ bf16 Bs[128 * 64];
  const int t = threadIdx.x, lane = t & 63, w = t >> 6;
  const int wm = w >> 1, wn = w & 1;
  const int m0 = blockIdx.x * 128, n0 = blockIdx.y * 128;

  f32x4 acc[4][4];
#pragma unroll
  for (int i = 0; i < 4; ++i)
#pragma unroll
    for (int j = 0; j < 4; ++j) acc[i][j] = (f32x4)0.0f;

  const int srow = t >> 3;
  const int sc = t & 7;

  for (int kt = 0; kt < 8; ++kt) {
    const int k0 = kt * 64;
#pragma unroll
    for (int i = 0; i < 4; ++i) {
      const int row = i * 32 + srow;
      uint4 va = *(const uint4*)(A + (size_t)(m0 + row) * 512 + k0 + sc * 8);
      uint4 vb = *(const uint4*)(Bt + (size_t)(n0 + row) * 512 + k0 + sc * 8);
      *(uint4*)((char*)As + row * 128 + ((sc ^ (row & 7)) << 4)) = va;
      *(uint4*)((char*)Bs + row * 128 + ((sc ^ (row & 7)) << 4)) = vb;
    }
    __syncthreads();
#pragma unroll
    for (int kk = 0; kk < 2; ++kk) {
      bf16x8 af[4], bfr[4];
#pragma unroll
      for (int mi = 0; mi < 4; ++mi) {
        const int r = wm * 64 + mi * 16 + (lane & 15);
        const int ch = kk * 4 + (lane >> 4);
        af[mi] = *(const bf16x8*)((const char*)As + r * 128 + ((ch ^ (r & 7)) << 4));
      }
#pragma unroll
      for (int ni = 0; ni < 4; ++ni) {
        const int r = wn * 64 + ni * 16 + (lane & 15);
        const int ch = kk * 4 + (lane >> 4);
        bfr[ni] = *(const bf16x8*)((const char*)Bs + r * 128 + ((ch ^ (r & 7)) << 4));
      }
#pragma unroll
      for (int mi = 0; mi < 4; ++mi)
#pragma unroll
        for (int ni = 0; ni < 4; ++ni)
          acc[mi][ni] = MFMA16(af[mi], bfr[ni], acc[mi][ni]);
    }
    __syncthreads();
  }

#pragma unroll
  for (int ni = 0; ni < 4; ++ni) {
    const int col = n0 + wn * 64 + ni * 16 + (lane & 15);
    const float bv = bias[col];
#pragma unroll
    for (int mi = 0; mi < 4; ++mi) {
      const int rb = m0 + wm * 64 + mi * 16 + ((lane >> 4) << 2);
#pragma unroll
      for (int r = 0; r < 4; ++r) {
        const int g = row2g(rb + r);
        const size_t idx = (size_t)g * 512 + col;
        out[idx] = acc[mi][ni][r] + bv + x[idx];
      }
    }
  }
}

// ---------------------------------------------------------------------------
extern "C" void kernel_launch(void* const* d_in, const int* in_sizes, int n_in,
                              void* d_out, int out_size, void* d_ws,
                              size_t ws_size, hipStream_t stream) {
  const float* x = (const float*)d_in[0];
  const float* gamma = (const float*)d_in[1];
  const float* beta = (const float*)d_in[2];
  const float* Wq_s = (const float*)d_in[3];
  const float* bq_s = (const float*)d_in[4];
  const float* Wq_m = (const float*)d_in[5];
  const float* bq_m = (const float*)d_in[6];
  const float* Wq_l = (const float*)d_in[7];
  const float* bq_l = (const float*)d_in[8];
  const float* Wout = (const float*)d_in[9];
  const float* bout = (const float*)d_in[10];
  float* out = (float*)d_out;

  char* ws = (char*)d_ws;
  bf16* h = (bf16*)(ws);                      // 57344 x 512
  bf16* qk = (bf16*)(ws + 58720256ull);       // 57344 x 1024
  bf16* vt = (bf16*)(ws + 176160768ull);      // 57344 x 512 (transposed per batch)
  bf16* wt_s = (bf16*)(ws + 234881024ull);
  bf16* wt_m = (bf16*)(ws + 236453888ull);
  bf16* wt_l = (bf16*)(ws + 238026752ull);
  bf16* wt_o = (bf16*)(ws + 239599616ull);

  dim3 tb(32, 8);
  transpose_w<<<dim3(48, 16), tb, 0, stream>>>(Wq_s, wt_s, 1536);
  transpose_w<<<dim3(48, 16), tb, 0, stream>>>(Wq_m, wt_m, 1536);
  transpose_w<<<dim3(48, 16), tb, 0, stream>>>(Wq_l, wt_l, 1536);
  transpose_w<<<dim3(16, 16), tb, 0, stream>>>(Wout, wt_o, 512);

  ln_kernel<<<14336, 256, 0, stream>>>(x, gamma, beta, h);

  qkv_gemm<<<dim3(64, 12), 256, 0, stream>>>(h, wt_s, bq_s, qk, vt, 9);
  qkv_gemm<<<dim3(128, 12), 256, 0, stream>>>(h + 8192ull * 512, wt_m, bq_m,
                                              qk + 8192ull * 1024,
                                              vt + 4194304ull, 10);
  qkv_gemm<<<dim3(256, 12), 256, 0, stream>>>(h + 24576ull * 512, wt_l, bq_l,
                                              qk + 24576ull * 1024,
                                              vt + 12582912ull, 11);

  const float scale = 0.04419417382415922f;  // 512^-0.5
  attn<<<256, 512, 0, stream>>>(qk, vt, h, 9, scale, 256);
  attn<<<512, 512, 0, stream>>>(qk + 8192ull * 1024, vt + 4194304ull,
                                h + 8192ull * 512, 10, scale, 512);
  attn<<<1024, 512, 0, stream>>>(qk + 24576ull * 1024, vt + 12582912ull,
                                 h + 24576ull * 512, 11, scale, 1024);

  out_gemm<<<dim3(448, 4), 256, 0, stream>>>(h, wt_o, bout, x, out);
}

// Round 3
// 817.889 us; speedup vs baseline: 1.3015x; 1.3015x over previous
//
#include <hip/hip_runtime.h>
#include <stdint.h>

typedef __bf16 bf16;
typedef __bf16 bf16x8 __attribute__((ext_vector_type(8)));
typedef __bf16 bf16x4 __attribute__((ext_vector_type(4)));
typedef float f32x4 __attribute__((ext_vector_type(4)));

#define MFMA16(a, b, c) __builtin_amdgcn_mfma_f32_16x16x32_bf16(a, b, c, 0, 0, 0)

typedef const __attribute__((address_space(1))) uint32_t* gas_t;
typedef __attribute__((address_space(3))) uint32_t* las_t;

__device__ __forceinline__ void gload16(const void* g, void* l) {
  __builtin_amdgcn_global_load_lds((gas_t)g, (las_t)l, 16, 0, 0);
}

// ---------------------------------------------------------------------------
// Shared 128x128xK GEMM core: global_load_lds staging (linear LDS dest,
// inverse-swizzled global source), XOR-swizzled ds_read, 16x16x32 MFMA.
// acc[mi][ni]: row = m0 + wm*64 + mi*16 + (lane>>4)*4 + r, col = n0 + wn*64 +
// ni*16 + (lane&15).
// ---------------------------------------------------------------------------
__device__ __forceinline__ void gemm_core(const bf16* __restrict__ A, int lda,
                                          const bf16* __restrict__ Bt, int ldb,
                                          int nk, int m0, int n0, bf16* As,
                                          bf16* Bs, f32x4 (*acc)[4]) {
  const int t = threadIdx.x;
  const int lane = t & 63, w = t >> 6;
  const int wm = w >> 1, wn = w & 1;
  const int r8 = lane >> 3;            // row within 8-row group
  const int cs = (lane & 7) ^ r8;      // inverse-swizzled source chunk

  for (int kt = 0; kt < nk; ++kt) {
    const int k0 = kt << 6;
#pragma unroll
    for (int i = 0; i < 4; ++i) {
      const int ii = (w << 2) + i;     // instr index 0..15
      const int row = (ii << 3) + r8;  // 0..127
      gload16(A + (size_t)(m0 + row) * lda + k0 + (cs << 3), As + (ii << 9));
      gload16(Bt + (size_t)(n0 + row) * ldb + k0 + (cs << 3), Bs + (ii << 9));
    }
    __syncthreads();
#pragma unroll
    for (int kk = 0; kk < 2; ++kk) {
      bf16x8 af[4], bfr[4];
#pragma unroll
      for (int mi = 0; mi < 4; ++mi) {
        const int r = wm * 64 + mi * 16 + (lane & 15);
        const int ch = kk * 4 + (lane >> 4);
        af[mi] = *(const bf16x8*)((const char*)As + r * 128 + ((ch ^ (r & 7)) << 4));
      }
#pragma unroll
      for (int ni = 0; ni < 4; ++ni) {
        const int r = wn * 64 + ni * 16 + (lane & 15);
        const int ch = kk * 4 + (lane >> 4);
        bfr[ni] = *(const bf16x8*)((const char*)Bs + r * 128 + ((ch ^ (r & 7)) << 4));
      }
#pragma unroll
      for (int mi = 0; mi < 4; ++mi)
#pragma unroll
        for (int ni = 0; ni < 4; ++ni)
          acc[mi][ni] = MFMA16(af[mi], bfr[ni], acc[mi][ni]);
    }
    __syncthreads();
  }
}

// ---------------------------------------------------------------------------
// Weight transpose + fp32->bf16 convert:  out[n][k] = (bf16) in[k][n]
// ---------------------------------------------------------------------------
__global__ __launch_bounds__(256) void transpose_w(const float* __restrict__ in,
                                                   bf16* __restrict__ out, int N) {
  __shared__ float tile[32][33];
  const int n0 = blockIdx.x * 32, k0 = blockIdx.y * 32;
  const int tx = threadIdx.x, ty = threadIdx.y;
#pragma unroll
  for (int i = 0; i < 4; ++i)
    tile[ty * 4 + i][tx] = in[(size_t)(k0 + ty * 4 + i) * N + n0 + tx];
  __syncthreads();
#pragma unroll
  for (int i = 0; i < 4; ++i)
    out[(size_t)(n0 + ty * 4 + i) * 512 + k0 + tx] = (bf16)tile[tx][ty * 4 + i];
}

// ---------------------------------------------------------------------------
// LayerNorm: x (57344 x 512) fp32 -> h bf16, scale-contiguous row blocks
// ---------------------------------------------------------------------------
__global__ __launch_bounds__(256) void ln_kernel(const float* __restrict__ x,
                                                 const float* __restrict__ gamma,
                                                 const float* __restrict__ beta,
                                                 bf16* __restrict__ h) {
  const int t = threadIdx.x, lane = t & 63, w = t >> 6;
  const int row = blockIdx.x * 4 + w;
  const float* xr = x + (size_t)row * 512 + lane * 8;
  float4 v0 = *(const float4*)xr;
  float4 v1 = *(const float4*)(xr + 4);
  float s = v0.x + v0.y + v0.z + v0.w + v1.x + v1.y + v1.z + v1.w;
  float q = v0.x * v0.x + v0.y * v0.y + v0.z * v0.z + v0.w * v0.w +
            v1.x * v1.x + v1.y * v1.y + v1.z * v1.z + v1.w * v1.w;
#pragma unroll
  for (int off = 1; off < 64; off <<= 1) {
    s += __shfl_xor(s, off);
    q += __shfl_xor(q, off);
  }
  const float mean = s * (1.0f / 512.0f);
  const float var = q * (1.0f / 512.0f) - mean * mean;
  const float rs = rsqrtf(var + 1e-5f);
  float4 g0 = *(const float4*)(gamma + lane * 8);
  float4 g1 = *(const float4*)(gamma + lane * 8 + 4);
  float4 b0 = *(const float4*)(beta + lane * 8);
  float4 b1 = *(const float4*)(beta + lane * 8 + 4);
  const int bb = row / 3584;
  const int sp = row - bb * 3584;
  size_t drow;
  if (sp < 512)
    drow = (size_t)bb * 512 + sp;
  else if (sp < 1536)
    drow = 8192 + (size_t)bb * 1024 + (sp - 512);
  else
    drow = 24576 + (size_t)bb * 2048 + (sp - 1536);
  bf16x8 ov = {(bf16)((v0.x - mean) * rs * g0.x + b0.x),
               (bf16)((v0.y - mean) * rs * g0.y + b0.y),
               (bf16)((v0.z - mean) * rs * g0.z + b0.z),
               (bf16)((v0.w - mean) * rs * g0.w + b0.w),
               (bf16)((v1.x - mean) * rs * g1.x + b1.x),
               (bf16)((v1.y - mean) * rs * g1.y + b1.y),
               (bf16)((v1.z - mean) * rs * g1.z + b1.z),
               (bf16)((v1.w - mean) * rs * g1.w + b1.w)};
  *(bf16x8*)(h + drow * 512 + lane * 8) = ov;
}

// ---------------------------------------------------------------------------
// QKV GEMM: C[M x 1536] = A[M x 512] * W + bias; Q,K -> qk (stride 1024),
// V -> vt transposed per batch (vt[b*512*L + d*L + kv]).
// ---------------------------------------------------------------------------
__global__ __launch_bounds__(256) void qkv_gemm(const bf16* __restrict__ A,
                                                const bf16* __restrict__ Bt,
                                                const float* __restrict__ bias,
                                                bf16* __restrict__ qk,
                                                bf16* __restrict__ vt, int l2L) {
  __shared__ bf16 As[128 * 64];
  __shared__ bf16 Bs[128 * 64];
  const int t = threadIdx.x, lane = t & 63, w = t >> 6;
  const int wm = w >> 1, wn = w & 1;
  const int m0 = blockIdx.x * 128, n0 = blockIdx.y * 128;
  const int L = 1 << l2L;

  f32x4 acc[4][4];
#pragma unroll
  for (int i = 0; i < 4; ++i)
#pragma unroll
    for (int j = 0; j < 4; ++j) acc[i][j] = (f32x4)0.0f;

  gemm_core(A, 512, Bt, 512, 8, m0, n0, As, Bs, acc);

  const bool isV = (n0 >= 1024);
#pragma unroll
  for (int ni = 0; ni < 4; ++ni) {
    const int col = n0 + wn * 64 + ni * 16 + (lane & 15);
    const float bv = bias[col];
#pragma unroll
    for (int mi = 0; mi < 4; ++mi) {
      const int rb = m0 + wm * 64 + mi * 16 + ((lane >> 4) << 2);
      if (!isV) {
#pragma unroll
        for (int r = 0; r < 4; ++r)
          qk[(size_t)(rb + r) * 1024 + col] = (bf16)(acc[mi][ni][r] + bv);
      } else {
        const int d = col - 1024;
        const int bi = rb >> l2L;
        const int kv = rb & (L - 1);
        bf16x4 pk = {(bf16)(acc[mi][ni][0] + bv), (bf16)(acc[mi][ni][1] + bv),
                     (bf16)(acc[mi][ni][2] + bv), (bf16)(acc[mi][ni][3] + bv)};
        *(bf16x4*)(vt + ((size_t)bi * 512 + d) * L + kv) = pk;
      }
    }
  }
}

// ---------------------------------------------------------------------------
// S = scale * (Q K^T) per batch -> sbuf bf16 [nb][L][L]
// qk: scale-base of combined Q/K buffer (stride 1024; +512 = K cols)
// grid: x = nb*(L/128), y = L/128
// ---------------------------------------------------------------------------
__global__ __launch_bounds__(256) void sgemm(const bf16* __restrict__ qk,
                                             bf16* __restrict__ sbuf, int l2L,
                                             int b0, float scale) {
  __shared__ bf16 As[128 * 64];
  __shared__ bf16 Bs[128 * 64];
  const int t = threadIdx.x, lane = t & 63, w = t >> 6;
  const int wm = w >> 1, wn = w & 1;
  const int L = 1 << l2L;
  const int mt = blockIdx.x & ((L >> 7) - 1);
  const int bi = blockIdx.x >> (l2L - 7);  // batch within this launch
  const int m0 = mt << 7, n0 = blockIdx.y << 7;

  const bf16* Ab = qk + (size_t)(b0 + bi) * L * 1024;
  const bf16* Bb = Ab + 512;
  bf16* C = sbuf + (size_t)bi * L * L;

  f32x4 acc[4][4];
#pragma unroll
  for (int i = 0; i < 4; ++i)
#pragma unroll
    for (int j = 0; j < 4; ++j) acc[i][j] = (f32x4)0.0f;

  gemm_core(Ab, 1024, Bb, 1024, 8, m0, n0, As, Bs, acc);

#pragma unroll
  for (int ni = 0; ni < 4; ++ni) {
    const int col = n0 + wn * 64 + ni * 16 + (lane & 15);
#pragma unroll
    for (int mi = 0; mi < 4; ++mi) {
      const int rb = m0 + wm * 64 + mi * 16 + ((lane >> 4) << 2);
#pragma unroll
      for (int r = 0; r < 4; ++r)
        C[(size_t)(rb + r) * L + col] = (bf16)(acc[mi][ni][r] * scale);
    }
  }
}

// ---------------------------------------------------------------------------
// Row softmax in place, one wave per row of length NV*64.
// ---------------------------------------------------------------------------
template <int NV>
__global__ __launch_bounds__(256) void softmax_rows(bf16* __restrict__ S) {
  const int t = threadIdx.x, lane = t & 63, w = t >> 6;
  bf16* r = S + ((size_t)blockIdx.x * 4 + w) * (NV * 64);
  bf16x8 raw[NV / 8];
  float f[NV];
#pragma unroll
  for (int i = 0; i < NV / 8; ++i)
    raw[i] = *(const bf16x8*)(r + (i * 64 + lane) * 8);
  float m = -INFINITY;
#pragma unroll
  for (int i = 0; i < NV / 8; ++i)
#pragma unroll
    for (int j = 0; j < 8; ++j) {
      f[i * 8 + j] = (float)raw[i][j];
      m = fmaxf(m, f[i * 8 + j]);
    }
#pragma unroll
  for (int off = 1; off < 64; off <<= 1) m = fmaxf(m, __shfl_xor(m, off));
  const float L2E = 1.44269504088896f;
  float s = 0.0f;
#pragma unroll
  for (int i = 0; i < NV; ++i) {
    f[i] = exp2f((f[i] - m) * L2E);
    s += f[i];
  }
#pragma unroll
  for (int off = 1; off < 64; off <<= 1) s += __shfl_xor(s, off);
  const float inv = 1.0f / s;
#pragma unroll
  for (int i = 0; i < NV / 8; ++i) {
    bf16x8 o;
#pragma unroll
    for (int j = 0; j < 8; ++j) o[j] = (bf16)(f[i * 8 + j] * inv);
    *(bf16x8*)(r + (i * 64 + lane) * 8) = o;
  }
}

// ---------------------------------------------------------------------------
// O = P * V : A = P (sbuf, lda=L), Bt = vt rows d (ldb=L), K = L.
// Writes O bf16 [L x 512] rows into o (scale-base of h region).
// grid: x = nb*(L/128), y = 4
// ---------------------------------------------------------------------------
__global__ __launch_bounds__(256) void pvgemm(const bf16* __restrict__ sbuf,
                                              const bf16* __restrict__ vt,
                                              bf16* __restrict__ o, int l2L,
                                              int b0) {
  __shared__ bf16 As[128 * 64];
  __shared__ bf16 Bs[128 * 64];
  const int t = threadIdx.x, lane = t & 63, w = t >> 6;
  const int wm = w >> 1, wn = w & 1;
  const int L = 1 << l2L;
  const int mt = blockIdx.x & ((L >> 7) - 1);
  const int bi = blockIdx.x >> (l2L - 7);
  const int b = b0 + bi;
  const int m0 = mt << 7, n0 = blockIdx.y << 7;

  const bf16* Ab = sbuf + (size_t)bi * L * L;
  const bf16* Bb = vt + (size_t)b * 512 * L;
  bf16* C = o + (size_t)b * L * 512;

  f32x4 acc[4][4];
#pragma unroll
  for (int i = 0; i < 4; ++i)
#pragma unroll
    for (int j = 0; j < 4; ++j) acc[i][j] = (f32x4)0.0f;

  gemm_core(Ab, L, Bb, L, L >> 6, m0, n0, As, Bs, acc);

#pragma unroll
  for (int ni = 0; ni < 4; ++ni) {
    const int col = n0 + wn * 64 + ni * 16 + (lane & 15);
#pragma unroll
    for (int mi = 0; mi < 4; ++mi) {
      const int rb = m0 + wm * 64 + mi * 16 + ((lane >> 4) << 2);
#pragma unroll
      for (int r = 0; r < 4; ++r)
        C[(size_t)(rb + r) * 512 + col] = (bf16)acc[mi][ni][r];
    }
  }
}

// ---------------------------------------------------------------------------
// Out projection + bias + residual (fp32 out), rows scattered back to
// (b, seq) interleaved layout via row2g.
// ---------------------------------------------------------------------------
__device__ __forceinline__ int row2g(int row) {
  if (row < 8192) return ((row >> 9) * 3584) + (row & 511);
  if (row < 24576) {
    const int r = row - 8192;
    return ((r >> 10) * 3584) + 512 + (r & 1023);
  }
  const int r = row - 24576;
  return ((r >> 11) * 3584) + 1536 + (r & 2047);
}

__global__ __launch_bounds__(256) void out_gemm(const bf16* __restrict__ A,
                                                const bf16* __restrict__ Bt,
                                                const float* __restrict__ bias,
                                                const float* __restrict__ x,
                                                float* __restrict__ out) {
  __shared__ bf16 As[128 * 64];
  __shared__ bf16 Bs[128 * 64];
  const int t = threadIdx.x, lane = t & 63, w = t >> 6;
  const int wm = w >> 1, wn = w & 1;
  const int m0 = blockIdx.x * 128, n0 = blockIdx.y * 128;

  f32x4 acc[4][4];
#pragma unroll
  for (int i = 0; i < 4; ++i)
#pragma unroll
    for (int j = 0; j < 4; ++j) acc[i][j] = (f32x4)0.0f;

  gemm_core(A, 512, Bt, 512, 8, m0, n0, As, Bs, acc);

#pragma unroll
  for (int ni = 0; ni < 4; ++ni) {
    const int col = n0 + wn * 64 + ni * 16 + (lane & 15);
    const float bv = bias[col];
#pragma unroll
    for (int mi = 0; mi < 4; ++mi) {
      const int rb = m0 + wm * 64 + mi * 16 + ((lane >> 4) << 2);
#pragma unroll
      for (int r = 0; r < 4; ++r) {
        const int g = row2g(rb + r);
        const size_t idx = (size_t)g * 512 + col;
        out[idx] = acc[mi][ni][r] + bv + x[idx];
      }
    }
  }
}

// ---------------------------------------------------------------------------
extern "C" void kernel_launch(void* const* d_in, const int* in_sizes, int n_in,
                              void* d_out, int out_size, void* d_ws,
                              size_t ws_size, hipStream_t stream) {
  const float* x = (const float*)d_in[0];
  const float* gamma = (const float*)d_in[1];
  const float* beta = (const float*)d_in[2];
  const float* Wq_s = (const float*)d_in[3];
  const float* bq_s = (const float*)d_in[4];
  const float* Wq_m = (const float*)d_in[5];
  const float* bq_m = (const float*)d_in[6];
  const float* Wq_l = (const float*)d_in[7];
  const float* bq_l = (const float*)d_in[8];
  const float* Wout = (const float*)d_in[9];
  const float* bout = (const float*)d_in[10];
  float* out = (float*)d_out;

  char* ws = (char*)d_ws;
  bf16* h = (bf16*)(ws);                      // 57344 x 512
  bf16* qk = (bf16*)(ws + 58720256ull);       // 57344 x 1024
  bf16* vt = (bf16*)(ws + 176160768ull);      // 57344 x 512 (V^T per batch)
  bf16* wt_s = (bf16*)(ws + 234881024ull);
  bf16* wt_m = (bf16*)(ws + 236453888ull);
  bf16* wt_l = (bf16*)(ws + 238026752ull);
  bf16* wt_o = (bf16*)(ws + 239599616ull);
  bf16* sbuf = (bf16*)d_out;                  // scratch until out_gemm

  dim3 tb(32, 8);
  transpose_w<<<dim3(48, 16), tb, 0, stream>>>(Wq_s, wt_s, 1536);
  transpose_w<<<dim3(48, 16), tb, 0, stream>>>(Wq_m, wt_m, 1536);
  transpose_w<<<dim3(48, 16), tb, 0, stream>>>(Wq_l, wt_l, 1536);
  transpose_w<<<dim3(16, 16), tb, 0, stream>>>(Wout, wt_o, 512);

  ln_kernel<<<14336, 256, 0, stream>>>(x, gamma, beta, h);

  qkv_gemm<<<dim3(64, 12), 256, 0, stream>>>(h, wt_s, bq_s, qk, vt, 9);
  qkv_gemm<<<dim3(128, 12), 256, 0, stream>>>(h + 8192ull * 512, wt_m, bq_m,
                                              qk + 8192ull * 1024,
                                              vt + 4194304ull, 10);
  qkv_gemm<<<dim3(256, 12), 256, 0, stream>>>(h + 24576ull * 512, wt_l, bq_l,
                                              qk + 24576ull * 1024,
                                              vt + 12582912ull, 11);

  const float scale = 0.04419417382415922f;  // 512^-0.5

  // S scale: L=512, 16 batches at once (S buf 8.4 MB)
  sgemm<<<dim3(64, 4), 256, 0, stream>>>(qk, sbuf, 9, 0, scale);
  softmax_rows<8><<<2048, 256, 0, stream>>>(sbuf);
  pvgemm<<<dim3(64, 4), 256, 0, stream>>>(sbuf, vt, h, 9, 0);

  // M scale: L=1024, 16 batches (33.5 MB)
  sgemm<<<dim3(128, 8), 256, 0, stream>>>(qk + 8192ull * 1024, sbuf, 10, 0,
                                          scale);
  softmax_rows<16><<<4096, 256, 0, stream>>>(sbuf);
  pvgemm<<<dim3(128, 4), 256, 0, stream>>>(sbuf, vt + 4194304ull,
                                           h + 8192ull * 512, 10, 0);

  // L scale: L=2048, two halves of 8 batches (67 MB each)
  for (int b0 = 0; b0 < 16; b0 += 8) {
    sgemm<<<dim3(128, 16), 256, 0, stream>>>(qk + 24576ull * 1024, sbuf, 11,
                                             b0, scale);
    softmax_rows<32><<<4096, 256, 0, stream>>>(sbuf);
    pvgemm<<<dim3(128, 4), 256, 0, stream>>>(sbuf, vt + 12582912ull,
                                             h + 24576ull * 512, 11, b0);
  }

  out_gemm<<<dim3(448, 4), 256, 0, stream>>>(h, wt_o, bout, x, out);
}

// Round 4
// 721.825 us; speedup vs baseline: 1.4747x; 1.1331x over previous
//
#include <hip/hip_runtime.h>
#include <stdint.h>

typedef __bf16 bf16;
typedef __bf16 bf16x8 __attribute__((ext_vector_type(8)));
typedef __bf16 bf16x4 __attribute__((ext_vector_type(4)));
typedef float f32x4 __attribute__((ext_vector_type(4)));

#define MFMA16(a, b, c) __builtin_amdgcn_mfma_f32_16x16x32_bf16(a, b, c, 0, 0, 0)

typedef const __attribute__((address_space(1))) uint32_t* gas_t;
typedef __attribute__((address_space(3))) uint32_t* las_t;

__device__ __forceinline__ void gload16(const void* g, void* l) {
  __builtin_amdgcn_global_load_lds((gas_t)g, (las_t)l, 16, 0, 0);
}

// ---------------------------------------------------------------------------
// Shared 128x128xK GEMM core: global_load_lds staging (linear LDS dest,
// inverse-swizzled global source), XOR-swizzled ds_read, 16x16x32 MFMA.
// acc[mi][ni]: row = m0 + wm*64 + mi*16 + (lane>>4)*4 + r, col = n0 + wn*64 +
// ni*16 + (lane&15).
// ---------------------------------------------------------------------------
__device__ __forceinline__ void gemm_core(const bf16* __restrict__ A, int lda,
                                          const bf16* __restrict__ Bt, int ldb,
                                          int nk, int m0, int n0, bf16* As,
                                          bf16* Bs, f32x4 (*acc)[4]) {
  const int t = threadIdx.x;
  const int lane = t & 63, w = t >> 6;
  const int wm = w >> 1, wn = w & 1;
  const int r8 = lane >> 3;            // row within 8-row group
  const int cs = (lane & 7) ^ r8;      // inverse-swizzled source chunk

  for (int kt = 0; kt < nk; ++kt) {
    const int k0 = kt << 6;
#pragma unroll
    for (int i = 0; i < 4; ++i) {
      const int ii = (w << 2) + i;     // instr index 0..15
      const int row = (ii << 3) + r8;  // 0..127
      gload16(A + (size_t)(m0 + row) * lda + k0 + (cs << 3), As + (ii << 9));
      gload16(Bt + (size_t)(n0 + row) * ldb + k0 + (cs << 3), Bs + (ii << 9));
    }
    __syncthreads();
#pragma unroll
    for (int kk = 0; kk < 2; ++kk) {
      bf16x8 af[4], bfr[4];
#pragma unroll
      for (int mi = 0; mi < 4; ++mi) {
        const int r = wm * 64 + mi * 16 + (lane & 15);
        const int ch = kk * 4 + (lane >> 4);
        af[mi] = *(const bf16x8*)((const char*)As + r * 128 + ((ch ^ (r & 7)) << 4));
      }
#pragma unroll
      for (int ni = 0; ni < 4; ++ni) {
        const int r = wn * 64 + ni * 16 + (lane & 15);
        const int ch = kk * 4 + (lane >> 4);
        bfr[ni] = *(const bf16x8*)((const char*)Bs + r * 128 + ((ch ^ (r & 7)) << 4));
      }
#pragma unroll
      for (int mi = 0; mi < 4; ++mi)
#pragma unroll
        for (int ni = 0; ni < 4; ++ni)
          acc[mi][ni] = MFMA16(af[mi], bfr[ni], acc[mi][ni]);
    }
    __syncthreads();
  }
}

// ---------------------------------------------------------------------------
// Epilogue transpose through LDS (16KB fp32 tile [32][128], XOR-swizzled).
// epi_put: one mi-slab of acc -> LDS. epi_get: 16 row-contiguous floats/thread.
// consumer mapping: lr = t>>3, local row = (lr>>4)*64 + mi*16 + (lr&15),
// local col c0 = (t&7)*16 .. +15.
// ---------------------------------------------------------------------------
__device__ __forceinline__ void epi_put(float* lds, const f32x4* accmi,
                                        int lane, int wm, int wn) {
#pragma unroll
  for (int ni = 0; ni < 4; ++ni) {
    const int c = wn * 64 + ni * 16 + (lane & 15);
    const int lr0 = wm * 16 + ((lane >> 4) << 2);
#pragma unroll
    for (int r = 0; r < 4; ++r) {
      const int lr = lr0 + r;
      lds[(lr << 7) + ((((c >> 2) ^ (lr & 7)) << 2) | (c & 3))] = accmi[ni][r];
    }
  }
}

__device__ __forceinline__ void epi_get(const float* lds, int t, f32x4* v) {
  const int lr = t >> 3, ch0 = (t & 7) << 2;
#pragma unroll
  for (int j = 0; j < 4; ++j)
    v[j] = *(const f32x4*)(lds + (lr << 7) + (((ch0 + j) ^ (lr & 7)) << 2));
}

// ---------------------------------------------------------------------------
// Weight transpose + fp32->bf16 convert:  out[n][k] = (bf16) in[k][n]
// ---------------------------------------------------------------------------
__global__ __launch_bounds__(256) void transpose_w(const float* __restrict__ in,
                                                   bf16* __restrict__ out, int N) {
  __shared__ float tile[32][33];
  const int n0 = blockIdx.x * 32, k0 = blockIdx.y * 32;
  const int tx = threadIdx.x, ty = threadIdx.y;
#pragma unroll
  for (int i = 0; i < 4; ++i)
    tile[ty * 4 + i][tx] = in[(size_t)(k0 + ty * 4 + i) * N + n0 + tx];
  __syncthreads();
#pragma unroll
  for (int i = 0; i < 4; ++i)
    out[(size_t)(n0 + ty * 4 + i) * 512 + k0 + tx] = (bf16)tile[tx][ty * 4 + i];
}

// ---------------------------------------------------------------------------
// LayerNorm: x (57344 x 512) fp32 -> h bf16, scale-contiguous row blocks
// ---------------------------------------------------------------------------
__global__ __launch_bounds__(256) void ln_kernel(const float* __restrict__ x,
                                                 const float* __restrict__ gamma,
                                                 const float* __restrict__ beta,
                                                 bf16* __restrict__ h) {
  const int t = threadIdx.x, lane = t & 63, w = t >> 6;
  const int row = blockIdx.x * 4 + w;
  const float* xr = x + (size_t)row * 512 + lane * 8;
  float4 v0 = *(const float4*)xr;
  float4 v1 = *(const float4*)(xr + 4);
  float s = v0.x + v0.y + v0.z + v0.w + v1.x + v1.y + v1.z + v1.w;
  float q = v0.x * v0.x + v0.y * v0.y + v0.z * v0.z + v0.w * v0.w +
            v1.x * v1.x + v1.y * v1.y + v1.z * v1.z + v1.w * v1.w;
#pragma unroll
  for (int off = 1; off < 64; off <<= 1) {
    s += __shfl_xor(s, off);
    q += __shfl_xor(q, off);
  }
  const float mean = s * (1.0f / 512.0f);
  const float var = q * (1.0f / 512.0f) - mean * mean;
  const float rs = rsqrtf(var + 1e-5f);
  float4 g0 = *(const float4*)(gamma + lane * 8);
  float4 g1 = *(const float4*)(gamma + lane * 8 + 4);
  float4 b0 = *(const float4*)(beta + lane * 8);
  float4 b1 = *(const float4*)(beta + lane * 8 + 4);
  const int bb = row / 3584;
  const int sp = row - bb * 3584;
  size_t drow;
  if (sp < 512)
    drow = (size_t)bb * 512 + sp;
  else if (sp < 1536)
    drow = 8192 + (size_t)bb * 1024 + (sp - 512);
  else
    drow = 24576 + (size_t)bb * 2048 + (sp - 1536);
  bf16x8 ov = {(bf16)((v0.x - mean) * rs * g0.x + b0.x),
               (bf16)((v0.y - mean) * rs * g0.y + b0.y),
               (bf16)((v0.z - mean) * rs * g0.z + b0.z),
               (bf16)((v0.w - mean) * rs * g0.w + b0.w),
               (bf16)((v1.x - mean) * rs * g1.x + b1.x),
               (bf16)((v1.y - mean) * rs * g1.y + b1.y),
               (bf16)((v1.z - mean) * rs * g1.z + b1.z),
               (bf16)((v1.w - mean) * rs * g1.w + b1.w)};
  *(bf16x8*)(h + drow * 512 + lane * 8) = ov;
}

// ---------------------------------------------------------------------------
// QKV GEMM: C[M x 1536] = A[M x 512] * W + bias; Q,K -> qk (stride 1024,
// coalesced via LDS-transposed epilogue), V -> vt transposed per batch.
// ---------------------------------------------------------------------------
__global__ __launch_bounds__(256) void qkv_gemm(const bf16* __restrict__ A,
                                                const bf16* __restrict__ Bt,
                                                const float* __restrict__ bias,
                                                bf16* __restrict__ qk,
                                                bf16* __restrict__ vt, int l2L) {
  __shared__ bf16 As[128 * 64];
  __shared__ bf16 Bs[128 * 64];
  const int t = threadIdx.x, lane = t & 63, w = t >> 6;
  const int wm = w >> 1, wn = w & 1;
  const int m0 = blockIdx.x * 128, n0 = blockIdx.y * 128;
  const int L = 1 << l2L;

  f32x4 acc[4][4];
#pragma unroll
  for (int i = 0; i < 4; ++i)
#pragma unroll
    for (int j = 0; j < 4; ++j) acc[i][j] = (f32x4)0.0f;

  gemm_core(A, 512, Bt, 512, 8, m0, n0, As, Bs, acc);

  if (n0 < 1024) {
    // Q/K: LDS-transposed epilogue, bf16x8 coalesced stores
    float* et = (float*)As;
    const int lr = t >> 3, c0l = (t & 7) << 4;
#pragma unroll
    for (int mi = 0; mi < 4; ++mi) {
      __syncthreads();
      epi_put(et, acc[mi], lane, wm, wn);
      __syncthreads();
      f32x4 v[4];
      epi_get(et, t, v);
      const int grow = m0 + ((lr >> 4) << 6) + mi * 16 + (lr & 15);
      const int gcol = n0 + c0l;
      bf16x8 o0, o1;
#pragma unroll
      for (int j = 0; j < 4; ++j) {
        float4 bv = *(const float4*)(bias + gcol + j * 4);
#pragma unroll
        for (int k = 0; k < 4; ++k) {
          const bf16 val = (bf16)(v[j][k] + ((const float*)&bv)[k]);
          if (j < 2) o0[j * 4 + k] = val;
          else o1[(j - 2) * 4 + k] = val;
        }
      }
      bf16* dst = qk + (size_t)grow * 1024 + gcol;
      *(bf16x8*)dst = o0;
      *(bf16x8*)(dst + 8) = o1;
    }
  } else {
    // V: store transposed (row-contiguity along kv) - already vectorized
#pragma unroll
    for (int ni = 0; ni < 4; ++ni) {
      const int col = n0 + wn * 64 + ni * 16 + (lane & 15);
      const float bv = bias[col];
#pragma unroll
      for (int mi = 0; mi < 4; ++mi) {
        const int rb = m0 + wm * 64 + mi * 16 + ((lane >> 4) << 2);
        const int d = col - 1024;
        const int bi = rb >> l2L;
        const int kv = rb & (L - 1);
        bf16x4 pk = {(bf16)(acc[mi][ni][0] + bv), (bf16)(acc[mi][ni][1] + bv),
                     (bf16)(acc[mi][ni][2] + bv), (bf16)(acc[mi][ni][3] + bv)};
        *(bf16x4*)(vt + ((size_t)bi * 512 + d) * L + kv) = pk;
      }
    }
  }
}

// ---------------------------------------------------------------------------
// S = scale * (Q K^T) per batch -> sbuf bf16 [nb][L][L]
// ---------------------------------------------------------------------------
__global__ __launch_bounds__(256) void sgemm(const bf16* __restrict__ qk,
                                             bf16* __restrict__ sbuf, int l2L,
                                             int b0, float scale) {
  __shared__ bf16 As[128 * 64];
  __shared__ bf16 Bs[128 * 64];
  const int t = threadIdx.x, lane = t & 63, w = t >> 6;
  const int wm = w >> 1, wn = w & 1;
  const int L = 1 << l2L;
  const int mt = blockIdx.x & ((L >> 7) - 1);
  const int bi = blockIdx.x >> (l2L - 7);
  const int m0 = mt << 7, n0 = blockIdx.y << 7;

  const bf16* Ab = qk + (size_t)(b0 + bi) * L * 1024;
  const bf16* Bb = Ab + 512;
  bf16* C = sbuf + (size_t)bi * L * L;

  f32x4 acc[4][4];
#pragma unroll
  for (int i = 0; i < 4; ++i)
#pragma unroll
    for (int j = 0; j < 4; ++j) acc[i][j] = (f32x4)0.0f;

  gemm_core(Ab, 1024, Bb, 1024, 8, m0, n0, As, Bs, acc);

  float* et = (float*)As;
  const int lr = t >> 3, c0l = (t & 7) << 4;
#pragma unroll
  for (int mi = 0; mi < 4; ++mi) {
    __syncthreads();
    epi_put(et, acc[mi], lane, wm, wn);
    __syncthreads();
    f32x4 v[4];
    epi_get(et, t, v);
    const int grow = m0 + ((lr >> 4) << 6) + mi * 16 + (lr & 15);
    bf16x8 o0, o1;
#pragma unroll
    for (int j = 0; j < 4; ++j)
#pragma unroll
      for (int k = 0; k < 4; ++k) {
        const bf16 val = (bf16)(v[j][k] * scale);
        if (j < 2) o0[j * 4 + k] = val;
        else o1[(j - 2) * 4 + k] = val;
      }
    bf16* dst = C + (size_t)grow * L + n0 + c0l;
    *(bf16x8*)dst = o0;
    *(bf16x8*)(dst + 8) = o1;
  }
}

// ---------------------------------------------------------------------------
// Row softmax in place, one wave per row of length NV*64.
// ---------------------------------------------------------------------------
template <int NV>
__global__ __launch_bounds__(256) void softmax_rows(bf16* __restrict__ S) {
  const int t = threadIdx.x, lane = t & 63, w = t >> 6;
  bf16* r = S + ((size_t)blockIdx.x * 4 + w) * (NV * 64);
  bf16x8 raw[NV / 8];
  float f[NV];
#pragma unroll
  for (int i = 0; i < NV / 8; ++i)
    raw[i] = *(const bf16x8*)(r + (i * 64 + lane) * 8);
  float m = -INFINITY;
#pragma unroll
  for (int i = 0; i < NV / 8; ++i)
#pragma unroll
    for (int j = 0; j < 8; ++j) {
      f[i * 8 + j] = (float)raw[i][j];
      m = fmaxf(m, f[i * 8 + j]);
    }
#pragma unroll
  for (int off = 1; off < 64; off <<= 1) m = fmaxf(m, __shfl_xor(m, off));
  const float L2E = 1.44269504088896f;
  float s = 0.0f;
#pragma unroll
  for (int i = 0; i < NV; ++i) {
    f[i] = exp2f((f[i] - m) * L2E);
    s += f[i];
  }
#pragma unroll
  for (int off = 1; off < 64; off <<= 1) s += __shfl_xor(s, off);
  const float inv = 1.0f / s;
#pragma unroll
  for (int i = 0; i < NV / 8; ++i) {
    bf16x8 o;
#pragma unroll
    for (int j = 0; j < 8; ++j) o[j] = (bf16)(f[i * 8 + j] * inv);
    *(bf16x8*)(r + (i * 64 + lane) * 8) = o;
  }
}

// ---------------------------------------------------------------------------
// O = P * V : A = P (sbuf, lda=L), Bt = vt rows d (ldb=L), K = L.
// ---------------------------------------------------------------------------
__global__ __launch_bounds__(256) void pvgemm(const bf16* __restrict__ sbuf,
                                              const bf16* __restrict__ vt,
                                              bf16* __restrict__ o, int l2L,
                                              int b0) {
  __shared__ bf16 As[128 * 64];
  __shared__ bf16 Bs[128 * 64];
  const int t = threadIdx.x, lane = t & 63, w = t >> 6;
  const int wm = w >> 1, wn = w & 1;
  const int L = 1 << l2L;
  const int mt = blockIdx.x & ((L >> 7) - 1);
  const int bi = blockIdx.x >> (l2L - 7);
  const int b = b0 + bi;
  const int m0 = mt << 7, n0 = blockIdx.y << 7;

  const bf16* Ab = sbuf + (size_t)bi * L * L;
  const bf16* Bb = vt + (size_t)b * 512 * L;
  bf16* C = o + (size_t)b * L * 512;

  f32x4 acc[4][4];
#pragma unroll
  for (int i = 0; i < 4; ++i)
#pragma unroll
    for (int j = 0; j < 4; ++j) acc[i][j] = (f32x4)0.0f;

  gemm_core(Ab, L, Bb, L, L >> 6, m0, n0, As, Bs, acc);

  float* et = (float*)As;
  const int lr = t >> 3, c0l = (t & 7) << 4;
#pragma unroll
  for (int mi = 0; mi < 4; ++mi) {
    __syncthreads();
    epi_put(et, acc[mi], lane, wm, wn);
    __syncthreads();
    f32x4 v[4];
    epi_get(et, t, v);
    const int grow = m0 + ((lr >> 4) << 6) + mi * 16 + (lr & 15);
    bf16x8 o0, o1;
#pragma unroll
    for (int j = 0; j < 4; ++j)
#pragma unroll
      for (int k = 0; k < 4; ++k) {
        const bf16 val = (bf16)v[j][k];
        if (j < 2) o0[j * 4 + k] = val;
        else o1[(j - 2) * 4 + k] = val;
      }
    bf16* dst = C + (size_t)grow * 512 + n0 + c0l;
    *(bf16x8*)dst = o0;
    *(bf16x8*)(dst + 8) = o1;
  }
}

// ---------------------------------------------------------------------------
// Out projection + bias + residual (fp32 out), coalesced float4 epilogue.
// 1-D grid, n-fastest + bijective XCD chunk swizzle (1792 blocks).
// ---------------------------------------------------------------------------
__device__ __forceinline__ int row2g(int row) {
  if (row < 8192) return ((row >> 9) * 3584) + (row & 511);
  if (row < 24576) {
    const int r = row - 8192;
    return ((r >> 10) * 3584) + 512 + (r & 1023);
  }
  const int r = row - 24576;
  return ((r >> 11) * 3584) + 1536 + (r & 2047);
}

__global__ __launch_bounds__(256) void out_gemm(const bf16* __restrict__ A,
                                                const bf16* __restrict__ Bt,
                                                const float* __restrict__ bias,
                                                const float* __restrict__ x,
                                                float* __restrict__ out) {
  __shared__ bf16 As[128 * 64];
  __shared__ bf16 Bs[128 * 64];
  const int t = threadIdx.x, lane = t & 63, w = t >> 6;
  const int wm = w >> 1, wn = w & 1;
  // 1792 blocks: XCD chunk swizzle (224/XCD), then n-fastest (4 n-tiles
  // sharing one A-panel run back-to-back on the same XCD -> L2 hits)
  const int lg = (blockIdx.x & 7) * 224 + (blockIdx.x >> 3);
  const int m0 = (lg >> 2) << 7;
  const int n0 = (lg & 3) << 7;

  f32x4 acc[4][4];
#pragma unroll
  for (int i = 0; i < 4; ++i)
#pragma unroll
    for (int j = 0; j < 4; ++j) acc[i][j] = (f32x4)0.0f;

  gemm_core(A, 512, Bt, 512, 8, m0, n0, As, Bs, acc);

  float* et = (float*)As;
  const int lr = t >> 3, c0l = (t & 7) << 4;
#pragma unroll
  for (int mi = 0; mi < 4; ++mi) {
    __syncthreads();
    epi_put(et, acc[mi], lane, wm, wn);
    __syncthreads();
    f32x4 v[4];
    epi_get(et, t, v);
    const int grow = m0 + ((lr >> 4) << 6) + mi * 16 + (lr & 15);
    const int g = row2g(grow);
    const int gcol = n0 + c0l;
    const float* xs = x + (size_t)g * 512 + gcol;
    float* os = out + (size_t)g * 512 + gcol;
#pragma unroll
    for (int j = 0; j < 4; ++j) {
      float4 bv = *(const float4*)(bias + gcol + j * 4);
      float4 xv = *(const float4*)(xs + j * 4);
      float4 ov;
      ov.x = v[j][0] + bv.x + xv.x;
      ov.y = v[j][1] + bv.y + xv.y;
      ov.z = v[j][2] + bv.z + xv.z;
      ov.w = v[j][3] + bv.w + xv.w;
      *(float4*)(os + j * 4) = ov;
    }
  }
}

// ---------------------------------------------------------------------------
extern "C" void kernel_launch(void* const* d_in, const int* in_sizes, int n_in,
                              void* d_out, int out_size, void* d_ws,
                              size_t ws_size, hipStream_t stream) {
  const float* x = (const float*)d_in[0];
  const float* gamma = (const float*)d_in[1];
  const float* beta = (const float*)d_in[2];
  const float* Wq_s = (const float*)d_in[3];
  const float* bq_s = (const float*)d_in[4];
  const float* Wq_m = (const float*)d_in[5];
  const float* bq_m = (const float*)d_in[6];
  const float* Wq_l = (const float*)d_in[7];
  const float* bq_l = (const float*)d_in[8];
  const float* Wout = (const float*)d_in[9];
  const float* bout = (const float*)d_in[10];
  float* out = (float*)d_out;

  char* ws = (char*)d_ws;
  bf16* h = (bf16*)(ws);                      // 57344 x 512
  bf16* qk = (bf16*)(ws + 58720256ull);       // 57344 x 1024
  bf16* vt = (bf16*)(ws + 176160768ull);      // 57344 x 512 (V^T per batch)
  bf16* wt_s = (bf16*)(ws + 234881024ull);
  bf16* wt_m = (bf16*)(ws + 236453888ull);
  bf16* wt_l = (bf16*)(ws + 238026752ull);
  bf16* wt_o = (bf16*)(ws + 239599616ull);
  bf16* sbuf = (bf16*)d_out;                  // scratch until out_gemm

  dim3 tb(32, 8);
  transpose_w<<<dim3(48, 16), tb, 0, stream>>>(Wq_s, wt_s, 1536);
  transpose_w<<<dim3(48, 16), tb, 0, stream>>>(Wq_m, wt_m, 1536);
  transpose_w<<<dim3(48, 16), tb, 0, stream>>>(Wq_l, wt_l, 1536);
  transpose_w<<<dim3(16, 16), tb, 0, stream>>>(Wout, wt_o, 512);

  ln_kernel<<<14336, 256, 0, stream>>>(x, gamma, beta, h);

  qkv_gemm<<<dim3(64, 12), 256, 0, stream>>>(h, wt_s, bq_s, qk, vt, 9);
  qkv_gemm<<<dim3(128, 12), 256, 0, stream>>>(h + 8192ull * 512, wt_m, bq_m,
                                              qk + 8192ull * 1024,
                                              vt + 4194304ull, 10);
  qkv_gemm<<<dim3(256, 12), 256, 0, stream>>>(h + 24576ull * 512, wt_l, bq_l,
                                              qk + 24576ull * 1024,
                                              vt + 12582912ull, 11);

  const float scale = 0.04419417382415922f;  // 512^-0.5

  // S scale: L=512, 16 batches at once (S buf 8.4 MB)
  sgemm<<<dim3(64, 4), 256, 0, stream>>>(qk, sbuf, 9, 0, scale);
  softmax_rows<8><<<2048, 256, 0, stream>>>(sbuf);
  pvgemm<<<dim3(64, 4), 256, 0, stream>>>(sbuf, vt, h, 9, 0);

  // M scale: L=1024, 16 batches (33.5 MB)
  sgemm<<<dim3(128, 8), 256, 0, stream>>>(qk + 8192ull * 1024, sbuf, 10, 0,
                                          scale);
  softmax_rows<16><<<4096, 256, 0, stream>>>(sbuf);
  pvgemm<<<dim3(128, 4), 256, 0, stream>>>(sbuf, vt + 4194304ull,
                                           h + 8192ull * 512, 10, 0);

  // L scale: L=2048, two halves of 8 batches (67 MB each)
  for (int b0 = 0; b0 < 16; b0 += 8) {
    sgemm<<<dim3(128, 16), 256, 0, stream>>>(qk + 24576ull * 1024, sbuf, 11,
                                             b0, scale);
    softmax_rows<32><<<4096, 256, 0, stream>>>(sbuf);
    pvgemm<<<dim3(128, 4), 256, 0, stream>>>(sbuf, vt + 12582912ull,
                                             h + 24576ull * 512, 11, b0);
  }

  out_gemm<<<1792, 256, 0, stream>>>(h, wt_o, bout, x, out);
}

// Round 5
// 699.750 us; speedup vs baseline: 1.5212x; 1.0315x over previous
//
#include <hip/hip_runtime.h>
#include <stdint.h>

typedef __bf16 bf16;
typedef __bf16 bf16x8 __attribute__((ext_vector_type(8)));
typedef __bf16 bf16x4 __attribute__((ext_vector_type(4)));
typedef float f32x4 __attribute__((ext_vector_type(4)));

#define MFMA16(a, b, c) __builtin_amdgcn_mfma_f32_16x16x32_bf16(a, b, c, 0, 0, 0)

typedef const __attribute__((address_space(1))) uint32_t* gas_t;
typedef __attribute__((address_space(3))) uint32_t* las_t;

__device__ __forceinline__ void gload16(const void* g, void* l) {
  __builtin_amdgcn_global_load_lds((gas_t)g, (las_t)l, 16, 0, 0);
}

// ---------------------------------------------------------------------------
// 128x128xK GEMM core, 2-phase pipelined (double-buffered LDS; next tile's
// global_load_lds issued BEFORE current tile's ds_read+MFMA so the load
// latency hides under compute; one barrier per K-step).
// LDS layout: linear dest for global_load_lds, inverse-swizzled global
// source, XOR-swizzled ds_read (verified R3/R4).
// acc[mi][ni]: row = m0 + wm*64 + mi*16 + (lane>>4)*4 + r,
//              col = n0 + wn*64 + ni*16 + (lane&15).
// ---------------------------------------------------------------------------
__device__ __forceinline__ void stage_tile(const bf16* __restrict__ A, int lda,
                                           const bf16* __restrict__ Bt, int ldb,
                                           int m0, int n0, int k0, bf16* Ad,
                                           bf16* Bd, int w, int r8, int cs) {
#pragma unroll
  for (int i = 0; i < 4; ++i) {
    const int ii = (w << 2) + i;     // instr index 0..15
    const int row = (ii << 3) + r8;  // 0..127
    gload16(A + (size_t)(m0 + row) * lda + k0 + (cs << 3), Ad + (ii << 9));
    gload16(Bt + (size_t)(n0 + row) * ldb + k0 + (cs << 3), Bd + (ii << 9));
  }
}

__device__ __forceinline__ void compute_tile(const bf16* As, const bf16* Bs,
                                             f32x4 (*acc)[4], int lane, int wm,
                                             int wn) {
#pragma unroll
  for (int kk = 0; kk < 2; ++kk) {
    bf16x8 af[4], bfr[4];
#pragma unroll
    for (int mi = 0; mi < 4; ++mi) {
      const int r = wm * 64 + mi * 16 + (lane & 15);
      const int ch = kk * 4 + (lane >> 4);
      af[mi] = *(const bf16x8*)((const char*)As + r * 128 + ((ch ^ (r & 7)) << 4));
    }
#pragma unroll
    for (int ni = 0; ni < 4; ++ni) {
      const int r = wn * 64 + ni * 16 + (lane & 15);
      const int ch = kk * 4 + (lane >> 4);
      bfr[ni] = *(const bf16x8*)((const char*)Bs + r * 128 + ((ch ^ (r & 7)) << 4));
    }
#pragma unroll
    for (int mi = 0; mi < 4; ++mi)
#pragma unroll
      for (int ni = 0; ni < 4; ++ni)
        acc[mi][ni] = MFMA16(af[mi], bfr[ni], acc[mi][ni]);
  }
}

__device__ __forceinline__ void gemm_core(const bf16* __restrict__ A, int lda,
                                          const bf16* __restrict__ Bt, int ldb,
                                          int nk, int m0, int n0,
                                          bf16 (*As)[128 * 64],
                                          bf16 (*Bs)[128 * 64],
                                          f32x4 (*acc)[4]) {
  const int t = threadIdx.x;
  const int lane = t & 63, w = t >> 6;
  const int wm = w >> 1, wn = w & 1;
  const int r8 = lane >> 3;
  const int cs = (lane & 7) ^ r8;

  stage_tile(A, lda, Bt, ldb, m0, n0, 0, As[0], Bs[0], w, r8, cs);
  __syncthreads();
  int cur = 0;
  for (int kt = 0; kt < nk; ++kt) {
    if (kt + 1 < nk)
      stage_tile(A, lda, Bt, ldb, m0, n0, (kt + 1) << 6, As[cur ^ 1],
                 Bs[cur ^ 1], w, r8, cs);
    compute_tile(As[cur], Bs[cur], acc, lane, wm, wn);
    __syncthreads();  // drains the just-issued stage (covered by compute)
    cur ^= 1;
  }
}

// ---------------------------------------------------------------------------
// Epilogue transpose through LDS (16KB fp32 tile [32][128], XOR-swizzled).
// ---------------------------------------------------------------------------
__device__ __forceinline__ void epi_put(float* lds, const f32x4* accmi,
                                        int lane, int wm, int wn) {
#pragma unroll
  for (int ni = 0; ni < 4; ++ni) {
    const int c = wn * 64 + ni * 16 + (lane & 15);
    const int lr0 = wm * 16 + ((lane >> 4) << 2);
#pragma unroll
    for (int r = 0; r < 4; ++r) {
      const int lr = lr0 + r;
      lds[(lr << 7) + ((((c >> 2) ^ (lr & 7)) << 2) | (c & 3))] = accmi[ni][r];
    }
  }
}

__device__ __forceinline__ void epi_get(const float* lds, int t, f32x4* v) {
  const int lr = t >> 3, ch0 = (t & 7) << 2;
#pragma unroll
  for (int j = 0; j < 4; ++j)
    v[j] = *(const f32x4*)(lds + (lr << 7) + (((ch0 + j) ^ (lr & 7)) << 2));
}

// ---------------------------------------------------------------------------
// Weight transpose + fp32->bf16 convert:  out[n][k] = (bf16) in[k][n]
// ---------------------------------------------------------------------------
__global__ __launch_bounds__(256) void transpose_w(const float* __restrict__ in,
                                                   bf16* __restrict__ out, int N) {
  __shared__ float tile[32][33];
  const int n0 = blockIdx.x * 32, k0 = blockIdx.y * 32;
  const int tx = threadIdx.x, ty = threadIdx.y;
#pragma unroll
  for (int i = 0; i < 4; ++i)
    tile[ty * 4 + i][tx] = in[(size_t)(k0 + ty * 4 + i) * N + n0 + tx];
  __syncthreads();
#pragma unroll
  for (int i = 0; i < 4; ++i)
    out[(size_t)(n0 + ty * 4 + i) * 512 + k0 + tx] = (bf16)tile[tx][ty * 4 + i];
}

// ---------------------------------------------------------------------------
// LayerNorm: x (57344 x 512) fp32 -> h bf16, scale-contiguous row blocks
// ---------------------------------------------------------------------------
__global__ __launch_bounds__(256) void ln_kernel(const float* __restrict__ x,
                                                 const float* __restrict__ gamma,
                                                 const float* __restrict__ beta,
                                                 bf16* __restrict__ h) {
  const int t = threadIdx.x, lane = t & 63, w = t >> 6;
  const int row = blockIdx.x * 4 + w;
  const float* xr = x + (size_t)row * 512 + lane * 8;
  float4 v0 = *(const float4*)xr;
  float4 v1 = *(const float4*)(xr + 4);
  float s = v0.x + v0.y + v0.z + v0.w + v1.x + v1.y + v1.z + v1.w;
  float q = v0.x * v0.x + v0.y * v0.y + v0.z * v0.z + v0.w * v0.w +
            v1.x * v1.x + v1.y * v1.y + v1.z * v1.z + v1.w * v1.w;
#pragma unroll
  for (int off = 1; off < 64; off <<= 1) {
    s += __shfl_xor(s, off);
    q += __shfl_xor(q, off);
  }
  const float mean = s * (1.0f / 512.0f);
  const float var = q * (1.0f / 512.0f) - mean * mean;
  const float rs = rsqrtf(var + 1e-5f);
  float4 g0 = *(const float4*)(gamma + lane * 8);
  float4 g1 = *(const float4*)(gamma + lane * 8 + 4);
  float4 b0 = *(const float4*)(beta + lane * 8);
  float4 b1 = *(const float4*)(beta + lane * 8 + 4);
  const int bb = row / 3584;
  const int sp = row - bb * 3584;
  size_t drow;
  if (sp < 512)
    drow = (size_t)bb * 512 + sp;
  else if (sp < 1536)
    drow = 8192 + (size_t)bb * 1024 + (sp - 512);
  else
    drow = 24576 + (size_t)bb * 2048 + (sp - 1536);
  bf16x8 ov = {(bf16)((v0.x - mean) * rs * g0.x + b0.x),
               (bf16)((v0.y - mean) * rs * g0.y + b0.y),
               (bf16)((v0.z - mean) * rs * g0.z + b0.z),
               (bf16)((v0.w - mean) * rs * g0.w + b0.w),
               (bf16)((v1.x - mean) * rs * g1.x + b1.x),
               (bf16)((v1.y - mean) * rs * g1.y + b1.y),
               (bf16)((v1.z - mean) * rs * g1.z + b1.z),
               (bf16)((v1.w - mean) * rs * g1.w + b1.w)};
  *(bf16x8*)(h + drow * 512 + lane * 8) = ov;
}

// ---------------------------------------------------------------------------
// QKV GEMM: 1-D grid (nblk = (M/128)*12 blocks), n-fastest within XCD chunk
// (12 consecutive blocks share one A-panel; per-XCD A range ~4MB -> L2 hits).
// Q,K -> qk (stride 1024, LDS-transposed epilogue), V -> vt transposed.
// ---------------------------------------------------------------------------
__global__ __launch_bounds__(256) void qkv_gemm(const bf16* __restrict__ A,
                                                const bf16* __restrict__ Bt,
                                                const float* __restrict__ bias,
                                                bf16* __restrict__ qk,
                                                bf16* __restrict__ vt, int l2L,
                                                int nblk) {
  __shared__ bf16 As[2][128 * 64];
  __shared__ bf16 Bs[2][128 * 64];
  const int t = threadIdx.x, lane = t & 63, w = t >> 6;
  const int wm = w >> 1, wn = w & 1;
  const int lg = (blockIdx.x & 7) * (nblk >> 3) + (blockIdx.x >> 3);
  const int m0 = (lg / 12) << 7;
  const int n0 = (lg % 12) << 7;
  const int L = 1 << l2L;

  f32x4 acc[4][4];
#pragma unroll
  for (int i = 0; i < 4; ++i)
#pragma unroll
    for (int j = 0; j < 4; ++j) acc[i][j] = (f32x4)0.0f;

  gemm_core(A, 512, Bt, 512, 8, m0, n0, As, Bs, acc);

  if (n0 < 1024) {
    // Q/K: LDS-transposed epilogue, bf16x8 coalesced stores
    float* et = (float*)As[0];
    const int lr = t >> 3, c0l = (t & 7) << 4;
#pragma unroll
    for (int mi = 0; mi < 4; ++mi) {
      __syncthreads();
      epi_put(et, acc[mi], lane, wm, wn);
      __syncthreads();
      f32x4 v[4];
      epi_get(et, t, v);
      const int grow = m0 + ((lr >> 4) << 6) + mi * 16 + (lr & 15);
      const int gcol = n0 + c0l;
      bf16x8 o0, o1;
#pragma unroll
      for (int j = 0; j < 4; ++j) {
        float4 bv = *(const float4*)(bias + gcol + j * 4);
#pragma unroll
        for (int k = 0; k < 4; ++k) {
          const bf16 val = (bf16)(v[j][k] + ((const float*)&bv)[k]);
          if (j < 2) o0[j * 4 + k] = val;
          else o1[(j - 2) * 4 + k] = val;
        }
      }
      bf16* dst = qk + (size_t)grow * 1024 + gcol;
      *(bf16x8*)dst = o0;
      *(bf16x8*)(dst + 8) = o1;
    }
  } else {
    // V: store transposed (row-contiguity along kv)
#pragma unroll
    for (int ni = 0; ni < 4; ++ni) {
      const int col = n0 + wn * 64 + ni * 16 + (lane & 15);
      const float bv = bias[col];
#pragma unroll
      for (int mi = 0; mi < 4; ++mi) {
        const int rb = m0 + wm * 64 + mi * 16 + ((lane >> 4) << 2);
        const int d = col - 1024;
        const int bi = rb >> l2L;
        const int kv = rb & (L - 1);
        bf16x4 pk = {(bf16)(acc[mi][ni][0] + bv), (bf16)(acc[mi][ni][1] + bv),
                     (bf16)(acc[mi][ni][2] + bv), (bf16)(acc[mi][ni][3] + bv)};
        *(bf16x4*)(vt + ((size_t)bi * 512 + d) * L + kv) = pk;
      }
    }
  }
}

// ---------------------------------------------------------------------------
// S = scale * (Q K^T) per batch -> sbuf bf16 [nb][L][L]
// ---------------------------------------------------------------------------
__global__ __launch_bounds__(256) void sgemm(const bf16* __restrict__ qk,
                                             bf16* __restrict__ sbuf, int l2L,
                                             int b0, float scale) {
  __shared__ bf16 As[2][128 * 64];
  __shared__ bf16 Bs[2][128 * 64];
  const int t = threadIdx.x, lane = t & 63, w = t >> 6;
  const int wm = w >> 1, wn = w & 1;
  const int L = 1 << l2L;
  const int mt = blockIdx.x & ((L >> 7) - 1);
  const int bi = blockIdx.x >> (l2L - 7);
  const int m0 = mt << 7, n0 = blockIdx.y << 7;

  const bf16* Ab = qk + (size_t)(b0 + bi) * L * 1024;
  const bf16* Bb = Ab + 512;
  bf16* C = sbuf + (size_t)bi * L * L;

  f32x4 acc[4][4];
#pragma unroll
  for (int i = 0; i < 4; ++i)
#pragma unroll
    for (int j = 0; j < 4; ++j) acc[i][j] = (f32x4)0.0f;

  gemm_core(Ab, 1024, Bb, 1024, 8, m0, n0, As, Bs, acc);

  float* et = (float*)As[0];
  const int lr = t >> 3, c0l = (t & 7) << 4;
#pragma unroll
  for (int mi = 0; mi < 4; ++mi) {
    __syncthreads();
    epi_put(et, acc[mi], lane, wm, wn);
    __syncthreads();
    f32x4 v[4];
    epi_get(et, t, v);
    const int grow = m0 + ((lr >> 4) << 6) + mi * 16 + (lr & 15);
    bf16x8 o0, o1;
#pragma unroll
    for (int j = 0; j < 4; ++j)
#pragma unroll
      for (int k = 0; k < 4; ++k) {
        const bf16 val = (bf16)(v[j][k] * scale);
        if (j < 2) o0[j * 4 + k] = val;
        else o1[(j - 2) * 4 + k] = val;
      }
    bf16* dst = C + (size_t)grow * L + n0 + c0l;
    *(bf16x8*)dst = o0;
    *(bf16x8*)(dst + 8) = o1;
  }
}

// ---------------------------------------------------------------------------
// Row softmax in place, one wave per row of length NV*64.
// ---------------------------------------------------------------------------
template <int NV>
__global__ __launch_bounds__(256) void softmax_rows(bf16* __restrict__ S) {
  const int t = threadIdx.x, lane = t & 63, w = t >> 6;
  bf16* r = S + ((size_t)blockIdx.x * 4 + w) * (NV * 64);
  bf16x8 raw[NV / 8];
  float f[NV];
#pragma unroll
  for (int i = 0; i < NV / 8; ++i)
    raw[i] = *(const bf16x8*)(r + (i * 64 + lane) * 8);
  float m = -INFINITY;
#pragma unroll
  for (int i = 0; i < NV / 8; ++i)
#pragma unroll
    for (int j = 0; j < 8; ++j) {
      f[i * 8 + j] = (float)raw[i][j];
      m = fmaxf(m, f[i * 8 + j]);
    }
#pragma unroll
  for (int off = 1; off < 64; off <<= 1) m = fmaxf(m, __shfl_xor(m, off));
  const float L2E = 1.44269504088896f;
  float s = 0.0f;
#pragma unroll
  for (int i = 0; i < NV; ++i) {
    f[i] = exp2f((f[i] - m) * L2E);
    s += f[i];
  }
#pragma unroll
  for (int off = 1; off < 64; off <<= 1) s += __shfl_xor(s, off);
  const float inv = 1.0f / s;
#pragma unroll
  for (int i = 0; i < NV / 8; ++i) {
    bf16x8 o;
#pragma unroll
    for (int j = 0; j < 8; ++j) o[j] = (bf16)(f[i * 8 + j] * inv);
    *(bf16x8*)(r + (i * 64 + lane) * 8) = o;
  }
}

// ---------------------------------------------------------------------------
// O = P * V : A = P (sbuf, lda=L), Bt = vt rows d (ldb=L), K = L.
// ---------------------------------------------------------------------------
__global__ __launch_bounds__(256) void pvgemm(const bf16* __restrict__ sbuf,
                                              const bf16* __restrict__ vt,
                                              bf16* __restrict__ o, int l2L,
                                              int b0) {
  __shared__ bf16 As[2][128 * 64];
  __shared__ bf16 Bs[2][128 * 64];
  const int t = threadIdx.x, lane = t & 63, w = t >> 6;
  const int wm = w >> 1, wn = w & 1;
  const int L = 1 << l2L;
  const int mt = blockIdx.x & ((L >> 7) - 1);
  const int bi = blockIdx.x >> (l2L - 7);
  const int b = b0 + bi;
  const int m0 = mt << 7, n0 = blockIdx.y << 7;

  const bf16* Ab = sbuf + (size_t)bi * L * L;
  const bf16* Bb = vt + (size_t)b * 512 * L;
  bf16* C = o + (size_t)b * L * 512;

  f32x4 acc[4][4];
#pragma unroll
  for (int i = 0; i < 4; ++i)
#pragma unroll
    for (int j = 0; j < 4; ++j) acc[i][j] = (f32x4)0.0f;

  gemm_core(Ab, L, Bb, L, L >> 6, m0, n0, As, Bs, acc);

  float* et = (float*)As[0];
  const int lr = t >> 3, c0l = (t & 7) << 4;
#pragma unroll
  for (int mi = 0; mi < 4; ++mi) {
    __syncthreads();
    epi_put(et, acc[mi], lane, wm, wn);
    __syncthreads();
    f32x4 v[4];
    epi_get(et, t, v);
    const int grow = m0 + ((lr >> 4) << 6) + mi * 16 + (lr & 15);
    bf16x8 o0, o1;
#pragma unroll
    for (int j = 0; j < 4; ++j)
#pragma unroll
      for (int k = 0; k < 4; ++k) {
        const bf16 val = (bf16)v[j][k];
        if (j < 2) o0[j * 4 + k] = val;
        else o1[(j - 2) * 4 + k] = val;
      }
    bf16* dst = C + (size_t)grow * 512 + n0 + c0l;
    *(bf16x8*)dst = o0;
    *(bf16x8*)(dst + 8) = o1;
  }
}

// ---------------------------------------------------------------------------
// Out projection + bias + residual (fp32 out), coalesced float4 epilogue.
// 1-D grid, n-fastest + bijective XCD chunk swizzle (1792 blocks).
// ---------------------------------------------------------------------------
__device__ __forceinline__ int row2g(int row) {
  if (row < 8192) return ((row >> 9) * 3584) + (row & 511);
  if (row < 24576) {
    const int r = row - 8192;
    return ((r >> 10) * 3584) + 512 + (r & 1023);
  }
  const int r = row - 24576;
  return ((r >> 11) * 3584) + 1536 + (r & 2047);
}

__global__ __launch_bounds__(256) void out_gemm(const bf16* __restrict__ A,
                                                const bf16* __restrict__ Bt,
                                                const float* __restrict__ bias,
                                                const float* __restrict__ x,
                                                float* __restrict__ out) {
  __shared__ bf16 As[2][128 * 64];
  __shared__ bf16 Bs[2][128 * 64];
  const int t = threadIdx.x, lane = t & 63, w = t >> 6;
  const int wm = w >> 1, wn = w & 1;
  const int lg = (blockIdx.x & 7) * 224 + (blockIdx.x >> 3);
  const int m0 = (lg >> 2) << 7;
  const int n0 = (lg & 3) << 7;

  f32x4 acc[4][4];
#pragma unroll
  for (int i = 0; i < 4; ++i)
#pragma unroll
    for (int j = 0; j < 4; ++j) acc[i][j] = (f32x4)0.0f;

  gemm_core(A, 512, Bt, 512, 8, m0, n0, As, Bs, acc);

  float* et = (float*)As[0];
  const int lr = t >> 3, c0l = (t & 7) << 4;
#pragma unroll
  for (int mi = 0; mi < 4; ++mi) {
    __syncthreads();
    epi_put(et, acc[mi], lane, wm, wn);
    __syncthreads();
    f32x4 v[4];
    epi_get(et, t, v);
    const int grow = m0 + ((lr >> 4) << 6) + mi * 16 + (lr & 15);
    const int g = row2g(grow);
    const int gcol = n0 + c0l;
    const float* xs = x + (size_t)g * 512 + gcol;
    float* os = out + (size_t)g * 512 + gcol;
#pragma unroll
    for (int j = 0; j < 4; ++j) {
      float4 bv = *(const float4*)(bias + gcol + j * 4);
      float4 xv = *(const float4*)(xs + j * 4);
      float4 ov;
      ov.x = v[j][0] + bv.x + xv.x;
      ov.y = v[j][1] + bv.y + xv.y;
      ov.z = v[j][2] + bv.z + xv.z;
      ov.w = v[j][3] + bv.w + xv.w;
      *(float4*)(os + j * 4) = ov;
    }
  }
}

// ---------------------------------------------------------------------------
extern "C" void kernel_launch(void* const* d_in, const int* in_sizes, int n_in,
                              void* d_out, int out_size, void* d_ws,
                              size_t ws_size, hipStream_t stream) {
  const float* x = (const float*)d_in[0];
  const float* gamma = (const float*)d_in[1];
  const float* beta = (const float*)d_in[2];
  const float* Wq_s = (const float*)d_in[3];
  const float* bq_s = (const float*)d_in[4];
  const float* Wq_m = (const float*)d_in[5];
  const float* bq_m = (const float*)d_in[6];
  const float* Wq_l = (const float*)d_in[7];
  const float* bq_l = (const float*)d_in[8];
  const float* Wout = (const float*)d_in[9];
  const float* bout = (const float*)d_in[10];
  float* out = (float*)d_out;

  char* ws = (char*)d_ws;
  bf16* h = (bf16*)(ws);                      // 57344 x 512
  bf16* qk = (bf16*)(ws + 58720256ull);       // 57344 x 1024
  bf16* vt = (bf16*)(ws + 176160768ull);      // 57344 x 512 (V^T per batch)
  bf16* wt_s = (bf16*)(ws + 234881024ull);
  bf16* wt_m = (bf16*)(ws + 236453888ull);
  bf16* wt_l = (bf16*)(ws + 238026752ull);
  bf16* wt_o = (bf16*)(ws + 239599616ull);
  bf16* sbuf = (bf16*)d_out;                  // scratch until out_gemm

  dim3 tb(32, 8);
  transpose_w<<<dim3(48, 16), tb, 0, stream>>>(Wq_s, wt_s, 1536);
  transpose_w<<<dim3(48, 16), tb, 0, stream>>>(Wq_m, wt_m, 1536);
  transpose_w<<<dim3(48, 16), tb, 0, stream>>>(Wq_l, wt_l, 1536);
  transpose_w<<<dim3(16, 16), tb, 0, stream>>>(Wout, wt_o, 512);

  ln_kernel<<<14336, 256, 0, stream>>>(x, gamma, beta, h);

  qkv_gemm<<<768, 256, 0, stream>>>(h, wt_s, bq_s, qk, vt, 9, 768);
  qkv_gemm<<<1536, 256, 0, stream>>>(h + 8192ull * 512, wt_m, bq_m,
                                     qk + 8192ull * 1024, vt + 4194304ull, 10,
                                     1536);
  qkv_gemm<<<3072, 256, 0, stream>>>(h + 24576ull * 512, wt_l, bq_l,
                                     qk + 24576ull * 1024, vt + 12582912ull,
                                     11, 3072);

  const float scale = 0.04419417382415922f;  // 512^-0.5

  // S scale: L=512, 16 batches at once (S buf 8.4 MB)
  sgemm<<<dim3(64, 4), 256, 0, stream>>>(qk, sbuf, 9, 0, scale);
  softmax_rows<8><<<2048, 256, 0, stream>>>(sbuf);
  pvgemm<<<dim3(64, 4), 256, 0, stream>>>(sbuf, vt, h, 9, 0);

  // M scale: L=1024, 16 batches (33.5 MB)
  sgemm<<<dim3(128, 8), 256, 0, stream>>>(qk + 8192ull * 1024, sbuf, 10, 0,
                                          scale);
  softmax_rows<16><<<4096, 256, 0, stream>>>(sbuf);
  pvgemm<<<dim3(128, 4), 256, 0, stream>>>(sbuf, vt + 4194304ull,
                                           h + 8192ull * 512, 10, 0);

  // L scale: L=2048, two halves of 8 batches (67 MB each)
  for (int b0 = 0; b0 < 16; b0 += 8) {
    sgemm<<<dim3(128, 16), 256, 0, stream>>>(qk + 24576ull * 1024, sbuf, 11,
                                             b0, scale);
    softmax_rows<32><<<4096, 256, 0, stream>>>(sbuf);
    pvgemm<<<dim3(128, 4), 256, 0, stream>>>(sbuf, vt + 12582912ull,
                                             h + 24576ull * 512, 11, b0);
  }

  out_gemm<<<1792, 256, 0, stream>>>(h, wt_o, bout, x, out);
}

// Round 6
// 618.100 us; speedup vs baseline: 1.7221x; 1.1321x over previous
//
#include <hip/hip_runtime.h>
#include <stdint.h>

typedef __bf16 bf16;
typedef __bf16 bf16x8 __attribute__((ext_vector_type(8)));
typedef __bf16 bf16x4 __attribute__((ext_vector_type(4)));
typedef float f32x4 __attribute__((ext_vector_type(4)));

#define MFMA16(a, b, c) __builtin_amdgcn_mfma_f32_16x16x32_bf16(a, b, c, 0, 0, 0)

typedef const __attribute__((address_space(1))) uint32_t* gas_t;
typedef __attribute__((address_space(3))) uint32_t* las_t;

__device__ __forceinline__ void gload16(const void* g, void* l) {
  __builtin_amdgcn_global_load_lds((gas_t)g, (las_t)l, 16, 0, 0);
}

// ---------------------------------------------------------------------------
// 128x128xK GEMM core, 2-phase pipelined (double-buffered LDS; next tile's
// global_load_lds issued BEFORE current tile's ds_read+MFMA; one barrier per
// K-step). Linear LDS dest + inverse-swizzled global source + XOR-swizzled
// ds_read (verified R3-R5).
// acc[mi][ni]: row = m0 + wm*64 + mi*16 + (lane>>4)*4 + r,
//              col = n0 + wn*64 + ni*16 + (lane&15).
// ---------------------------------------------------------------------------
__device__ __forceinline__ void stage_tile(const bf16* __restrict__ A, int lda,
                                           const bf16* __restrict__ Bt, int ldb,
                                           int m0, int n0, int k0, bf16* Ad,
                                           bf16* Bd, int w, int r8, int cs) {
#pragma unroll
  for (int i = 0; i < 4; ++i) {
    const int ii = (w << 2) + i;     // instr index 0..15
    const int row = (ii << 3) + r8;  // 0..127
    gload16(A + (size_t)(m0 + row) * lda + k0 + (cs << 3), Ad + (ii << 9));
    gload16(Bt + (size_t)(n0 + row) * ldb + k0 + (cs << 3), Bd + (ii << 9));
  }
}

__device__ __forceinline__ void compute_tile(const bf16* As, const bf16* Bs,
                                             f32x4 (*acc)[4], int lane, int wm,
                                             int wn) {
#pragma unroll
  for (int kk = 0; kk < 2; ++kk) {
    bf16x8 af[4], bfr[4];
#pragma unroll
    for (int mi = 0; mi < 4; ++mi) {
      const int r = wm * 64 + mi * 16 + (lane & 15);
      const int ch = kk * 4 + (lane >> 4);
      af[mi] = *(const bf16x8*)((const char*)As + r * 128 + ((ch ^ (r & 7)) << 4));
    }
#pragma unroll
    for (int ni = 0; ni < 4; ++ni) {
      const int r = wn * 64 + ni * 16 + (lane & 15);
      const int ch = kk * 4 + (lane >> 4);
      bfr[ni] = *(const bf16x8*)((const char*)Bs + r * 128 + ((ch ^ (r & 7)) << 4));
    }
#pragma unroll
    for (int mi = 0; mi < 4; ++mi)
#pragma unroll
      for (int ni = 0; ni < 4; ++ni)
        acc[mi][ni] = MFMA16(af[mi], bfr[ni], acc[mi][ni]);
  }
}

// smem: [4][128*64] bf16; A buffers = smem[0..1], B buffers = smem[2..3]
__device__ __forceinline__ void gemm_core(const bf16* __restrict__ A, int lda,
                                          const bf16* __restrict__ Bt, int ldb,
                                          int nk, int m0, int n0,
                                          bf16 (*smem)[128 * 64],
                                          f32x4 (*acc)[4]) {
  const int t = threadIdx.x;
  const int lane = t & 63, w = t >> 6;
  const int wm = w >> 1, wn = w & 1;
  const int r8 = lane >> 3;
  const int cs = (lane & 7) ^ r8;

  stage_tile(A, lda, Bt, ldb, m0, n0, 0, smem[0], smem[2], w, r8, cs);
  __syncthreads();
  int cur = 0;
  for (int kt = 0; kt < nk; ++kt) {
    if (kt + 1 < nk)
      stage_tile(A, lda, Bt, ldb, m0, n0, (kt + 1) << 6, smem[cur ^ 1],
                 smem[2 + (cur ^ 1)], w, r8, cs);
    compute_tile(smem[cur], smem[2 + cur], acc, lane, wm, wn);
    __syncthreads();
    cur ^= 1;
  }
}

// ---------------------------------------------------------------------------
// Epilogue transpose through LDS: ALL 4 mi-slabs at once into the full 64KB
// (4 x 16KB fp32 tiles, XOR-swizzled), ONE barrier, then coalesced stores.
// ---------------------------------------------------------------------------
__device__ __forceinline__ void epi_put(float* lds, const f32x4* accmi,
                                        int lane, int wm, int wn) {
#pragma unroll
  for (int ni = 0; ni < 4; ++ni) {
    const int c = wn * 64 + ni * 16 + (lane & 15);
    const int lr0 = wm * 16 + ((lane >> 4) << 2);
#pragma unroll
    for (int r = 0; r < 4; ++r) {
      const int lr = lr0 + r;
      lds[(lr << 7) + ((((c >> 2) ^ (lr & 7)) << 2) | (c & 3))] = accmi[ni][r];
    }
  }
}

__device__ __forceinline__ void epi_get(const float* lds, int t, f32x4* v) {
  const int lr = t >> 3, ch0 = (t & 7) << 2;
#pragma unroll
  for (int j = 0; j < 4; ++j)
    v[j] = *(const f32x4*)(lds + (lr << 7) + (((ch0 + j) ^ (lr & 7)) << 2));
}

// ---------------------------------------------------------------------------
// All weight transposes in one launch. id<768: Ws, <1536: Wm, <2304: Wl,
// else Wout. out[n][k] = (bf16) in[k][n].
// ---------------------------------------------------------------------------
__global__ __launch_bounds__(256) void transpose_all(
    const float* __restrict__ Ws, const float* __restrict__ Wm,
    const float* __restrict__ Wl, const float* __restrict__ Wo,
    bf16* __restrict__ os, bf16* __restrict__ om, bf16* __restrict__ ol,
    bf16* __restrict__ oo) {
  __shared__ float tile[32][33];
  const int id = blockIdx.x;
  const float* in;
  bf16* outp;
  int N, bx;
  if (id < 768) { in = Ws; outp = os; N = 1536; bx = id; }
  else if (id < 1536) { in = Wm; outp = om; N = 1536; bx = id - 768; }
  else if (id < 2304) { in = Wl; outp = ol; N = 1536; bx = id - 1536; }
  else { in = Wo; outp = oo; N = 512; bx = id - 2304; }
  const int nbx = N >> 5;
  const int n0 = (bx % nbx) * 32, k0 = (bx / nbx) * 32;
  const int tx = threadIdx.x, ty = threadIdx.y;
#pragma unroll
  for (int i = 0; i < 4; ++i)
    tile[ty * 4 + i][tx] = in[(size_t)(k0 + ty * 4 + i) * N + n0 + tx];
  __syncthreads();
#pragma unroll
  for (int i = 0; i < 4; ++i)
    outp[(size_t)(n0 + ty * 4 + i) * 512 + k0 + tx] = (bf16)tile[tx][ty * 4 + i];
}

// ---------------------------------------------------------------------------
// LayerNorm: x (57344 x 512) fp32 -> h bf16, scale-contiguous row blocks
// ---------------------------------------------------------------------------
__global__ __launch_bounds__(256) void ln_kernel(const float* __restrict__ x,
                                                 const float* __restrict__ gamma,
                                                 const float* __restrict__ beta,
                                                 bf16* __restrict__ h) {
  const int t = threadIdx.x, lane = t & 63, w = t >> 6;
  const int row = blockIdx.x * 4 + w;
  const float* xr = x + (size_t)row * 512 + lane * 8;
  float4 v0 = *(const float4*)xr;
  float4 v1 = *(const float4*)(xr + 4);
  float s = v0.x + v0.y + v0.z + v0.w + v1.x + v1.y + v1.z + v1.w;
  float q = v0.x * v0.x + v0.y * v0.y + v0.z * v0.z + v0.w * v0.w +
            v1.x * v1.x + v1.y * v1.y + v1.z * v1.z + v1.w * v1.w;
#pragma unroll
  for (int off = 1; off < 64; off <<= 1) {
    s += __shfl_xor(s, off);
    q += __shfl_xor(q, off);
  }
  const float mean = s * (1.0f / 512.0f);
  const float var = q * (1.0f / 512.0f) - mean * mean;
  const float rs = rsqrtf(var + 1e-5f);
  float4 g0 = *(const float4*)(gamma + lane * 8);
  float4 g1 = *(const float4*)(gamma + lane * 8 + 4);
  float4 b0 = *(const float4*)(beta + lane * 8);
  float4 b1 = *(const float4*)(beta + lane * 8 + 4);
  const int bb = row / 3584;
  const int sp = row - bb * 3584;
  size_t drow;
  if (sp < 512)
    drow = (size_t)bb * 512 + sp;
  else if (sp < 1536)
    drow = 8192 + (size_t)bb * 1024 + (sp - 512);
  else
    drow = 24576 + (size_t)bb * 2048 + (sp - 1536);
  bf16x8 ov = {(bf16)((v0.x - mean) * rs * g0.x + b0.x),
               (bf16)((v0.y - mean) * rs * g0.y + b0.y),
               (bf16)((v0.z - mean) * rs * g0.z + b0.z),
               (bf16)((v0.w - mean) * rs * g0.w + b0.w),
               (bf16)((v1.x - mean) * rs * g1.x + b1.x),
               (bf16)((v1.y - mean) * rs * g1.y + b1.y),
               (bf16)((v1.z - mean) * rs * g1.z + b1.z),
               (bf16)((v1.w - mean) * rs * g1.w + b1.w)};
  *(bf16x8*)(h + drow * 512 + lane * 8) = ov;
}

// ---------------------------------------------------------------------------
// QKV GEMM: 1-D grid, n-fastest within XCD chunk. Q,K -> qk (stride 1024),
// V -> vt transposed per batch.
// ---------------------------------------------------------------------------
__global__ __launch_bounds__(256) void qkv_gemm(const bf16* __restrict__ A,
                                                const bf16* __restrict__ Bt,
                                                const float* __restrict__ bias,
                                                bf16* __restrict__ qk,
                                                bf16* __restrict__ vt, int l2L,
                                                int nblk) {
  __shared__ bf16 smem[4][128 * 64];
  const int t = threadIdx.x, lane = t & 63, w = t >> 6;
  const int wm = w >> 1, wn = w & 1;
  const int lg = (blockIdx.x & 7) * (nblk >> 3) + (blockIdx.x >> 3);
  const int m0 = (lg / 12) << 7;
  const int n0 = (lg % 12) << 7;
  const int L = 1 << l2L;

  f32x4 acc[4][4];
#pragma unroll
  for (int i = 0; i < 4; ++i)
#pragma unroll
    for (int j = 0; j < 4; ++j) acc[i][j] = (f32x4)0.0f;

  gemm_core(A, 512, Bt, 512, 8, m0, n0, smem, acc);

  if (n0 < 1024) {
    float* et = (float*)smem;
#pragma unroll
    for (int mi = 0; mi < 4; ++mi) epi_put(et + (mi << 12), acc[mi], lane, wm, wn);
    __syncthreads();
    const int lr = t >> 3, c0l = (t & 7) << 4;
    const int gcol = n0 + c0l;
#pragma unroll
    for (int mi = 0; mi < 4; ++mi) {
      f32x4 v[4];
      epi_get(et + (mi << 12), t, v);
      const int grow = m0 + ((lr >> 4) << 6) + mi * 16 + (lr & 15);
      bf16x8 o0, o1;
#pragma unroll
      for (int j = 0; j < 4; ++j) {
        float4 bv = *(const float4*)(bias + gcol + j * 4);
#pragma unroll
        for (int k = 0; k < 4; ++k) {
          const bf16 val = (bf16)(v[j][k] + ((const float*)&bv)[k]);
          if (j < 2) o0[j * 4 + k] = val;
          else o1[(j - 2) * 4 + k] = val;
        }
      }
      bf16* dst = qk + (size_t)grow * 1024 + gcol;
      *(bf16x8*)dst = o0;
      *(bf16x8*)(dst + 8) = o1;
    }
  } else {
    // V: store transposed (4 lanes' bf16x4 combine to 32B runs along kv)
#pragma unroll
    for (int ni = 0; ni < 4; ++ni) {
      const int col = n0 + wn * 64 + ni * 16 + (lane & 15);
      const float bv = bias[col];
#pragma unroll
      for (int mi = 0; mi < 4; ++mi) {
        const int rb = m0 + wm * 64 + mi * 16 + ((lane >> 4) << 2);
        const int d = col - 1024;
        const int bi = rb >> l2L;
        const int kv = rb & (L - 1);
        bf16x4 pk = {(bf16)(acc[mi][ni][0] + bv), (bf16)(acc[mi][ni][1] + bv),
                     (bf16)(acc[mi][ni][2] + bv), (bf16)(acc[mi][ni][3] + bv)};
        *(bf16x4*)(vt + ((size_t)bi * 512 + d) * L + kv) = pk;
      }
    }
  }
}

// ---------------------------------------------------------------------------
// S = scale * (Q K^T) per batch -> sbuf bf16 [nb][L][L]
// 1-D grid, batch-major / n-fastest within XCD chunk (one batch's K panel
// pins in one XCD L2 at the L scale).
// ---------------------------------------------------------------------------
__global__ __launch_bounds__(256) void sgemm(const bf16* __restrict__ qk,
                                             bf16* __restrict__ sbuf, int l2L,
                                             int b0, float scale, int nblk) {
  __shared__ bf16 smem[4][128 * 64];
  const int t = threadIdx.x, lane = t & 63, w = t >> 6;
  const int wm = w >> 1, wn = w & 1;
  const int L = 1 << l2L;
  const int l2nt = l2L - 7;
  const int lg = (blockIdx.x & 7) * (nblk >> 3) + (blockIdx.x >> 3);
  const int bi = lg >> (2 * l2nt);
  const int rem = lg & ((1 << (2 * l2nt)) - 1);
  const int m0 = (rem >> l2nt) << 7;
  const int n0 = (rem & ((1 << l2nt) - 1)) << 7;

  const bf16* Ab = qk + (size_t)(b0 + bi) * L * 1024;
  const bf16* Bb = Ab + 512;
  bf16* C = sbuf + (size_t)bi * L * L;

  f32x4 acc[4][4];
#pragma unroll
  for (int i = 0; i < 4; ++i)
#pragma unroll
    for (int j = 0; j < 4; ++j) acc[i][j] = (f32x4)0.0f;

  gemm_core(Ab, 1024, Bb, 1024, 8, m0, n0, smem, acc);

  float* et = (float*)smem;
#pragma unroll
  for (int mi = 0; mi < 4; ++mi) epi_put(et + (mi << 12), acc[mi], lane, wm, wn);
  __syncthreads();
  const int lr = t >> 3, c0l = (t & 7) << 4;
#pragma unroll
  for (int mi = 0; mi < 4; ++mi) {
    f32x4 v[4];
    epi_get(et + (mi << 12), t, v);
    const int grow = m0 + ((lr >> 4) << 6) + mi * 16 + (lr & 15);
    bf16x8 o0, o1;
#pragma unroll
    for (int j = 0; j < 4; ++j)
#pragma unroll
      for (int k = 0; k < 4; ++k) {
        const bf16 val = (bf16)(v[j][k] * scale);
        if (j < 2) o0[j * 4 + k] = val;
        else o1[(j - 2) * 4 + k] = val;
      }
    bf16* dst = C + (size_t)grow * L + n0 + c0l;
    *(bf16x8*)dst = o0;
    *(bf16x8*)(dst + 8) = o1;
  }
}

// ---------------------------------------------------------------------------
// Row softmax in place, one wave per row of length NV*64.
// ---------------------------------------------------------------------------
template <int NV>
__global__ __launch_bounds__(256) void softmax_rows(bf16* __restrict__ S) {
  const int t = threadIdx.x, lane = t & 63, w = t >> 6;
  bf16* r = S + ((size_t)blockIdx.x * 4 + w) * (NV * 64);
  bf16x8 raw[NV / 8];
  float f[NV];
#pragma unroll
  for (int i = 0; i < NV / 8; ++i)
    raw[i] = *(const bf16x8*)(r + (i * 64 + lane) * 8);
  float m = -INFINITY;
#pragma unroll
  for (int i = 0; i < NV / 8; ++i)
#pragma unroll
    for (int j = 0; j < 8; ++j) {
      f[i * 8 + j] = (float)raw[i][j];
      m = fmaxf(m, f[i * 8 + j]);
    }
#pragma unroll
  for (int off = 1; off < 64; off <<= 1) m = fmaxf(m, __shfl_xor(m, off));
  const float L2E = 1.44269504088896f;
  float s = 0.0f;
#pragma unroll
  for (int i = 0; i < NV; ++i) {
    f[i] = exp2f((f[i] - m) * L2E);
    s += f[i];
  }
#pragma unroll
  for (int off = 1; off < 64; off <<= 1) s += __shfl_xor(s, off);
  const float inv = 1.0f / s;
#pragma unroll
  for (int i = 0; i < NV / 8; ++i) {
    bf16x8 o;
#pragma unroll
    for (int j = 0; j < 8; ++j) o[j] = (bf16)(f[i * 8 + j] * inv);
    *(bf16x8*)(r + (i * 64 + lane) * 8) = o;
  }
}

// ---------------------------------------------------------------------------
// O = P * V. 1-D grid, batch-major / n-fastest within XCD chunk (V^T panel
// of a batch <= 2MB pins in L2).
// ---------------------------------------------------------------------------
__global__ __launch_bounds__(256) void pvgemm(const bf16* __restrict__ sbuf,
                                              const bf16* __restrict__ vt,
                                              bf16* __restrict__ o, int l2L,
                                              int b0, int nblk) {
  __shared__ bf16 smem[4][128 * 64];
  const int t = threadIdx.x, lane = t & 63, w = t >> 6;
  const int wm = w >> 1, wn = w & 1;
  const int L = 1 << l2L;
  const int l2nt = l2L - 7;
  const int lg = (blockIdx.x & 7) * (nblk >> 3) + (blockIdx.x >> 3);
  const int bi = lg >> (l2nt + 2);
  const int rem = lg & ((1 << (l2nt + 2)) - 1);
  const int m0 = (rem >> 2) << 7;
  const int n0 = (rem & 3) << 7;
  const int b = b0 + bi;

  const bf16* Ab = sbuf + (size_t)bi * L * L;
  const bf16* Bb = vt + (size_t)b * 512 * L;
  bf16* C = o + (size_t)b * L * 512;

  f32x4 acc[4][4];
#pragma unroll
  for (int i = 0; i < 4; ++i)
#pragma unroll
    for (int j = 0; j < 4; ++j) acc[i][j] = (f32x4)0.0f;

  gemm_core(Ab, L, Bb, L, L >> 6, m0, n0, smem, acc);

  float* et = (float*)smem;
#pragma unroll
  for (int mi = 0; mi < 4; ++mi) epi_put(et + (mi << 12), acc[mi], lane, wm, wn);
  __syncthreads();
  const int lr = t >> 3, c0l = (t & 7) << 4;
#pragma unroll
  for (int mi = 0; mi < 4; ++mi) {
    f32x4 v[4];
    epi_get(et + (mi << 12), t, v);
    const int grow = m0 + ((lr >> 4) << 6) + mi * 16 + (lr & 15);
    bf16x8 o0, o1;
#pragma unroll
    for (int j = 0; j < 4; ++j)
#pragma unroll
      for (int k = 0; k < 4; ++k) {
        const bf16 val = (bf16)v[j][k];
        if (j < 2) o0[j * 4 + k] = val;
        else o1[(j - 2) * 4 + k] = val;
      }
    bf16* dst = C + (size_t)grow * 512 + n0 + c0l;
    *(bf16x8*)dst = o0;
    *(bf16x8*)(dst + 8) = o1;
  }
}

// ---------------------------------------------------------------------------
// Out projection + bias + residual (fp32 out), single-barrier epilogue.
// ---------------------------------------------------------------------------
__device__ __forceinline__ int row2g(int row) {
  if (row < 8192) return ((row >> 9) * 3584) + (row & 511);
  if (row < 24576) {
    const int r = row - 8192;
    return ((r >> 10) * 3584) + 512 + (r & 1023);
  }
  const int r = row - 24576;
  return ((r >> 11) * 3584) + 1536 + (r & 2047);
}

__global__ __launch_bounds__(256) void out_gemm(const bf16* __restrict__ A,
                                                const bf16* __restrict__ Bt,
                                                const float* __restrict__ bias,
                                                const float* __restrict__ x,
                                                float* __restrict__ out) {
  __shared__ bf16 smem[4][128 * 64];
  const int t = threadIdx.x, lane = t & 63, w = t >> 6;
  const int wm = w >> 1, wn = w & 1;
  const int lg = (blockIdx.x & 7) * 224 + (blockIdx.x >> 3);
  const int m0 = (lg >> 2) << 7;
  const int n0 = (lg & 3) << 7;

  f32x4 acc[4][4];
#pragma unroll
  for (int i = 0; i < 4; ++i)
#pragma unroll
    for (int j = 0; j < 4; ++j) acc[i][j] = (f32x4)0.0f;

  gemm_core(A, 512, Bt, 512, 8, m0, n0, smem, acc);

  float* et = (float*)smem;
#pragma unroll
  for (int mi = 0; mi < 4; ++mi) epi_put(et + (mi << 12), acc[mi], lane, wm, wn);
  __syncthreads();
  const int lr = t >> 3, c0l = (t & 7) << 4;
  const int gcol = n0 + c0l;
#pragma unroll
  for (int mi = 0; mi < 4; ++mi) {
    f32x4 v[4];
    epi_get(et + (mi << 12), t, v);
    const int grow = m0 + ((lr >> 4) << 6) + mi * 16 + (lr & 15);
    const int g = row2g(grow);
    const float* xs = x + (size_t)g * 512 + gcol;
    float* os = out + (size_t)g * 512 + gcol;
#pragma unroll
    for (int j = 0; j < 4; ++j) {
      float4 bv = *(const float4*)(bias + gcol + j * 4);
      float4 xv = *(const float4*)(xs + j * 4);
      float4 ov;
      ov.x = v[j][0] + bv.x + xv.x;
      ov.y = v[j][1] + bv.y + xv.y;
      ov.z = v[j][2] + bv.z + xv.z;
      ov.w = v[j][3] + bv.w + xv.w;
      *(float4*)(os + j * 4) = ov;
    }
  }
}

// ---------------------------------------------------------------------------
extern "C" void kernel_launch(void* const* d_in, const int* in_sizes, int n_in,
                              void* d_out, int out_size, void* d_ws,
                              size_t ws_size, hipStream_t stream) {
  const float* x = (const float*)d_in[0];
  const float* gamma = (const float*)d_in[1];
  const float* beta = (const float*)d_in[2];
  const float* Wq_s = (const float*)d_in[3];
  const float* bq_s = (const float*)d_in[4];
  const float* Wq_m = (const float*)d_in[5];
  const float* bq_m = (const float*)d_in[6];
  const float* Wq_l = (const float*)d_in[7];
  const float* bq_l = (const float*)d_in[8];
  const float* Wout = (const float*)d_in[9];
  const float* bout = (const float*)d_in[10];
  float* out = (float*)d_out;

  char* ws = (char*)d_ws;
  bf16* h = (bf16*)(ws);                      // 57344 x 512
  bf16* qk = (bf16*)(ws + 58720256ull);       // 57344 x 1024
  bf16* vt = (bf16*)(ws + 176160768ull);      // 57344 x 512 (V^T per batch)
  bf16* wt_s = (bf16*)(ws + 234881024ull);
  bf16* wt_m = (bf16*)(ws + 236453888ull);
  bf16* wt_l = (bf16*)(ws + 238026752ull);
  bf16* wt_o = (bf16*)(ws + 239599616ull);
  bf16* sbuf = (bf16*)d_out;                  // scratch until out_gemm

  transpose_all<<<2560, dim3(32, 8), 0, stream>>>(Wq_s, Wq_m, Wq_l, Wout, wt_s,
                                                  wt_m, wt_l, wt_o);

  ln_kernel<<<14336, 256, 0, stream>>>(x, gamma, beta, h);

  qkv_gemm<<<768, 256, 0, stream>>>(h, wt_s, bq_s, qk, vt, 9, 768);
  qkv_gemm<<<1536, 256, 0, stream>>>(h + 8192ull * 512, wt_m, bq_m,
                                     qk + 8192ull * 1024, vt + 4194304ull, 10,
                                     1536);
  qkv_gemm<<<3072, 256, 0, stream>>>(h + 24576ull * 512, wt_l, bq_l,
                                     qk + 24576ull * 1024, vt + 12582912ull,
                                     11, 3072);

  const float scale = 0.04419417382415922f;  // 512^-0.5

  // S scale: L=512, 16 batches (S buf 8.4 MB)
  sgemm<<<256, 256, 0, stream>>>(qk, sbuf, 9, 0, scale, 256);
  softmax_rows<8><<<2048, 256, 0, stream>>>(sbuf);
  pvgemm<<<256, 256, 0, stream>>>(sbuf, vt, h, 9, 0, 256);

  // M scale: L=1024, 16 batches (33.5 MB)
  sgemm<<<1024, 256, 0, stream>>>(qk + 8192ull * 1024, sbuf, 10, 0, scale,
                                  1024);
  softmax_rows<16><<<4096, 256, 0, stream>>>(sbuf);
  pvgemm<<<512, 256, 0, stream>>>(sbuf, vt + 4194304ull, h + 8192ull * 512, 10,
                                  0, 512);

  // L scale: L=2048, two halves of 8 batches (67 MB each)
  for (int b0 = 0; b0 < 16; b0 += 8) {
    sgemm<<<2048, 256, 0, stream>>>(qk + 24576ull * 1024, sbuf, 11, b0, scale,
                                    2048);
    softmax_rows<32><<<4096, 256, 0, stream>>>(sbuf);
    pvgemm<<<512, 256, 0, stream>>>(sbuf, vt + 12582912ull, h + 24576ull * 512,
                                    11, b0, 512);
  }

  out_gemm<<<1792, 256, 0, stream>>>(h, wt_o, bout, x, out);
}